// Round 1
// baseline (1954.109 us; speedup 1.0000x reference)
//
#include <hip/hip_runtime.h>

// Problem constants
#define NN 50000
#define EE 800000
// D = 64, 2D = 128, L = 5

// ---------------------------------------------------------------------------
// Edge kernel: per edge e, lane d:
//   h_src = first ? node_emb[x[src]][d] : relu(bn2_prev(y2[src][d]))
//   ee    = be[d] + sum_k ea[e][k]*We[k][d]
//   atomicAdd(agg[dst][d], relu(h_src + ee))
// One wave (64 lanes) per edge; 4 edges per 256-thread block; grid-stride.
// BN2 scale/shift computed per-thread from stats (wave-uniform inputs, cheap).
// ---------------------------------------------------------------------------
__global__ __launch_bounds__(256) void edge_kernel(
    const int* __restrict__ ei, const float* __restrict__ ea,
    const float* __restrict__ We, const float* __restrict__ be,
    const int* __restrict__ x, const float* __restrict__ nemb,
    const float* __restrict__ y2, const float* __restrict__ st2,
    const float* __restrict__ g2p, const float* __restrict__ bb2p,
    float* __restrict__ agg, const int first)
{
    const int t = threadIdx.x;
    const int d = t & 63;
    const int sub = t >> 6;

    // per-lane constants (registers, no LDS needed)
    float scd = 0.f, shd = 0.f;
    if (!first) {
        const float m = st2[d] * (1.0f / NN);
        const float v = fmaxf(st2[64 + d] * (1.0f / NN) - m * m, 0.0f);
        const float r = rsqrtf(v + 1e-5f);
        scd = g2p[d] * r;
        shd = bb2p[d] - m * scd;
    }
    const float bed = be[d];
    float w0 = We[0 * 64 + d], w1 = We[1 * 64 + d], w2 = We[2 * 64 + d],
          w3 = We[3 * 64 + d], w4 = We[4 * 64 + d], w5 = We[5 * 64 + d],
          w6 = We[6 * 64 + d];

    for (int g = blockIdx.x; g < (EE / 4); g += gridDim.x) {
        const int e = (g << 2) + sub;
        const int src = ei[e];
        const int dst = ei[EE + e];
        float hs;
        if (first) {
            hs = nemb[(x[src] << 6) + d];
        } else {
            hs = fmaxf(y2[(src << 6) + d] * scd + shd, 0.f);
        }
        const int eb = e * 7;
        float v = bed;
        v = fmaf(ea[eb + 0], w0, v);
        v = fmaf(ea[eb + 1], w1, v);
        v = fmaf(ea[eb + 2], w2, v);
        v = fmaf(ea[eb + 3], w3, v);
        v = fmaf(ea[eb + 4], w4, v);
        v = fmaf(ea[eb + 5], w5, v);
        v = fmaf(ea[eb + 6], w6, v);
        v = fmaxf(hs + v, 0.f);
        atomicAdd(&agg[(dst << 6) + d], v);
    }
}

// ---------------------------------------------------------------------------
// MM1: y1 = z @ W1 + b1  where z = (1+eps)*h + agg,
//      h = first ? node_emb[x] : relu(bn2_prev(y2)).
// Tile: 128 rows x 128 cols, K=64 in chunks of 32.
// Thread tile 8x8, rows strided by 16 (conflict-free pitch-33 LDS reads).
// Also accumulates column sum / sumsq of y1 into st1 via shfl + atomics.
// ---------------------------------------------------------------------------
__global__ __launch_bounds__(256) void mm1_kernel(
    const float* __restrict__ agg,
    const int* __restrict__ x, const float* __restrict__ nemb,
    const float* __restrict__ y2, const float* __restrict__ st2,
    const float* __restrict__ g2p, const float* __restrict__ bb2p,
    const float* __restrict__ epsp,
    const float* __restrict__ W1, const float* __restrict__ b1,
    float* __restrict__ y1, float* __restrict__ st1, const int first)
{
    __shared__ float As[128][33];
    __shared__ float Bs[32][128];
    __shared__ float sc2[64], sh2[64];
    const int t = threadIdx.x;
    if (t < 64) {
        if (!first) {
            const float m = st2[t] * (1.0f / NN);
            const float v = fmaxf(st2[64 + t] * (1.0f / NN) - m * m, 0.0f);
            const float r = rsqrtf(v + 1e-5f);
            const float sc = g2p[t] * r;
            sc2[t] = sc; sh2[t] = bb2p[t] - m * sc;
        } else { sc2[t] = 0.f; sh2[t] = 0.f; }
    }
    const float e1 = 1.0f + epsp[0];
    const int r0 = blockIdx.x * 128;
    const int rowg = t & 15;        // rows rowg + 16*j, j<8
    const int colg = t >> 4;        // cols colg*8 .. +7
    const int cbase = colg << 3;

    float acc[8][8];
#pragma unroll
    for (int j = 0; j < 8; ++j)
#pragma unroll
        for (int c = 0; c < 8; ++c) acc[j][c] = 0.f;

    for (int kc = 0; kc < 64; kc += 32) {
        __syncthreads();
        // stage A: 128 rows x 32 k  (1024 float4)
        for (int i = t; i < 1024; i += 256) {
            const int row = i >> 3;
            const int c4 = (i & 7) << 2;
            const int r = r0 + row;
            float vx = 0.f, vy = 0.f, vz = 0.f, vw = 0.f;
            if (r < NN) {
                const int f4 = (r << 4) + (kc >> 2) + (i & 7);
                const float4 av = ((const float4*)agg)[f4];
                float hx, hy, hz, hw;
                if (first) {
                    const float4 hv = ((const float4*)nemb)[(x[r] << 4) + (kc >> 2) + (i & 7)];
                    hx = hv.x; hy = hv.y; hz = hv.z; hw = hv.w;
                } else {
                    const float4 yv = ((const float4*)y2)[f4];
                    const int k0 = kc + c4;
                    hx = fmaxf(yv.x * sc2[k0 + 0] + sh2[k0 + 0], 0.f);
                    hy = fmaxf(yv.y * sc2[k0 + 1] + sh2[k0 + 1], 0.f);
                    hz = fmaxf(yv.z * sc2[k0 + 2] + sh2[k0 + 2], 0.f);
                    hw = fmaxf(yv.w * sc2[k0 + 3] + sh2[k0 + 3], 0.f);
                }
                vx = e1 * hx + av.x; vy = e1 * hy + av.y;
                vz = e1 * hz + av.z; vw = e1 * hw + av.w;
            }
            As[row][c4 + 0] = vx; As[row][c4 + 1] = vy;
            As[row][c4 + 2] = vz; As[row][c4 + 3] = vw;
        }
        // stage B: W1 rows kc..kc+31 x 128 cols (1024 float4, contiguous)
        for (int i = t; i < 1024; i += 256) {
            const int k = i >> 5;
            const int c4i = i & 31;
            ((float4*)&Bs[k][0])[c4i] = ((const float4*)W1)[((kc + k) << 5) + c4i];
        }
        __syncthreads();
#pragma unroll 4
        for (int k = 0; k < 32; ++k) {
            float a[8];
#pragma unroll
            for (int j = 0; j < 8; ++j) a[j] = As[rowg + (j << 4)][k];
            const float4 b0 = *(const float4*)&Bs[k][cbase];
            const float4 b1r = *(const float4*)&Bs[k][cbase + 4];
            const float b[8] = {b0.x, b0.y, b0.z, b0.w, b1r.x, b1r.y, b1r.z, b1r.w};
#pragma unroll
            for (int j = 0; j < 8; ++j)
#pragma unroll
                for (int c = 0; c < 8; ++c)
                    acc[j][c] = fmaf(a[j], b[c], acc[j][c]);
        }
    }
    // epilogue: add bias, store y1, accumulate stats
    float bv[8];
#pragma unroll
    for (int c = 0; c < 8; ++c) bv[c] = b1[cbase + c];
    float s[8], sq[8];
#pragma unroll
    for (int c = 0; c < 8; ++c) { s[c] = 0.f; sq[c] = 0.f; }
#pragma unroll
    for (int j = 0; j < 8; ++j) {
        const int r = r0 + rowg + (j << 4);
        if (r < NN) {
            float y[8];
#pragma unroll
            for (int c = 0; c < 8; ++c) y[c] = acc[j][c] + bv[c];
            *(float4*)&y1[(r << 7) + cbase] = make_float4(y[0], y[1], y[2], y[3]);
            *(float4*)&y1[(r << 7) + cbase + 4] = make_float4(y[4], y[5], y[6], y[7]);
#pragma unroll
            for (int c = 0; c < 8; ++c) { s[c] += y[c]; sq[c] += y[c] * y[c]; }
        }
    }
#pragma unroll
    for (int c = 0; c < 8; ++c) {
#pragma unroll
        for (int off = 8; off > 0; off >>= 1) {
            s[c] += __shfl_down(s[c], off, 16);
            sq[c] += __shfl_down(sq[c], off, 16);
        }
    }
    if (rowg == 0) {
#pragma unroll
        for (int c = 0; c < 8; ++c) {
            atomicAdd(&st1[cbase + c], s[c]);
            atomicAdd(&st1[128 + cbase + c], sq[c]);
        }
    }
}

// ---------------------------------------------------------------------------
// MM2: y2 = a @ W2 + b2  where a = relu(bn1(y1)).
// Tile: 64 rows x 64 cols, K=128 in chunks of 32. Thread tile 4x4,
// rows strided by 16. Accumulates stats of y2 into st2.
// ---------------------------------------------------------------------------
__global__ __launch_bounds__(256) void mm2_kernel(
    const float* __restrict__ y1, const float* __restrict__ st1,
    const float* __restrict__ g1, const float* __restrict__ bb1,
    const float* __restrict__ W2, const float* __restrict__ b2,
    float* __restrict__ y2, float* __restrict__ st2)
{
    __shared__ float As[64][33];
    __shared__ float Bs[32][64];
    __shared__ float sc1[128], sh1[128];
    const int t = threadIdx.x;
    if (t < 128) {
        const float m = st1[t] * (1.0f / NN);
        const float v = fmaxf(st1[128 + t] * (1.0f / NN) - m * m, 0.0f);
        const float r = rsqrtf(v + 1e-5f);
        const float sc = g1[t] * r;
        sc1[t] = sc; sh1[t] = bb1[t] - m * sc;
    }
    const int r0 = blockIdx.x * 64;
    const int rowg = t & 15;        // rows rowg + 16*j, j<4
    const int colg = t >> 4;        // cols colg*4 .. +3
    const int cbase = colg << 2;

    float acc[4][4];
#pragma unroll
    for (int j = 0; j < 4; ++j)
#pragma unroll
        for (int c = 0; c < 4; ++c) acc[j][c] = 0.f;

    for (int kc = 0; kc < 128; kc += 32) {
        __syncthreads();
        // stage A: 64 rows x 32 k (512 float4), apply bn1+relu on load
        for (int i = t; i < 512; i += 256) {
            const int row = i >> 3;
            const int c4 = (i & 7) << 2;
            const int r = r0 + row;
            float ax = 0.f, ay = 0.f, az = 0.f, aw = 0.f;
            if (r < NN) {
                const float4 yv = ((const float4*)y1)[(r << 5) + (kc >> 2) + (i & 7)];
                const int k0 = kc + c4;
                ax = fmaxf(yv.x * sc1[k0 + 0] + sh1[k0 + 0], 0.f);
                ay = fmaxf(yv.y * sc1[k0 + 1] + sh1[k0 + 1], 0.f);
                az = fmaxf(yv.z * sc1[k0 + 2] + sh1[k0 + 2], 0.f);
                aw = fmaxf(yv.w * sc1[k0 + 3] + sh1[k0 + 3], 0.f);
            }
            As[row][c4 + 0] = ax; As[row][c4 + 1] = ay;
            As[row][c4 + 2] = az; As[row][c4 + 3] = aw;
        }
        // stage B: W2 rows kc..kc+31 x 64 cols (512 float4, contiguous)
        for (int i = t; i < 512; i += 256) {
            const int k = i >> 4;
            const int c4i = i & 15;
            ((float4*)&Bs[k][0])[c4i] = ((const float4*)W2)[((kc + k) << 4) + c4i];
        }
        __syncthreads();
#pragma unroll 4
        for (int k = 0; k < 32; ++k) {
            float a[4];
#pragma unroll
            for (int j = 0; j < 4; ++j) a[j] = As[rowg + (j << 4)][k];
            const float4 bv4 = *(const float4*)&Bs[k][cbase];
            const float b[4] = {bv4.x, bv4.y, bv4.z, bv4.w};
#pragma unroll
            for (int j = 0; j < 4; ++j)
#pragma unroll
                for (int c = 0; c < 4; ++c)
                    acc[j][c] = fmaf(a[j], b[c], acc[j][c]);
        }
    }
    // epilogue
    float b2v[4];
#pragma unroll
    for (int c = 0; c < 4; ++c) b2v[c] = b2[cbase + c];
    float s[4], sq[4];
#pragma unroll
    for (int c = 0; c < 4; ++c) { s[c] = 0.f; sq[c] = 0.f; }
#pragma unroll
    for (int j = 0; j < 4; ++j) {
        const int r = r0 + rowg + (j << 4);
        if (r < NN) {
            float y[4];
#pragma unroll
            for (int c = 0; c < 4; ++c) y[c] = acc[j][c] + b2v[c];
            *(float4*)&y2[(r << 6) + cbase] = make_float4(y[0], y[1], y[2], y[3]);
#pragma unroll
            for (int c = 0; c < 4; ++c) { s[c] += y[c]; sq[c] += y[c] * y[c]; }
        }
    }
#pragma unroll
    for (int c = 0; c < 4; ++c) {
#pragma unroll
        for (int off = 8; off > 0; off >>= 1) {
            s[c] += __shfl_down(s[c], off, 16);
            sq[c] += __shfl_down(sq[c], off, 16);
        }
    }
    if (rowg == 0) {
#pragma unroll
        for (int c = 0; c < 4; ++c) {
            atomicAdd(&st2[cbase + c], s[c]);
            atomicAdd(&st2[64 + cbase + c], sq[c]);
        }
    }
}

// ---------------------------------------------------------------------------
// Final: out = bn2(y2) of layer 4, no relu (relu_flag false on last layer).
// ---------------------------------------------------------------------------
__global__ __launch_bounds__(256) void final_kernel(
    const float* __restrict__ y2, const float* __restrict__ st2,
    const float* __restrict__ g2, const float* __restrict__ bb2,
    float* __restrict__ out)
{
    const int i = (blockIdx.x << 8) + threadIdx.x;
    if (i >= NN * 64) return;
    const int d = i & 63;
    const float m = st2[d] * (1.0f / NN);
    const float v = fmaxf(st2[64 + d] * (1.0f / NN) - m * m, 0.0f);
    const float r = rsqrtf(v + 1e-5f);
    const float sc = g2[d] * r;
    const float sh = bb2[d] - m * sc;
    out[i] = y2[i] * sc + sh;
}

extern "C" void kernel_launch(void* const* d_in, const int* in_sizes, int n_in,
                              void* d_out, int out_size, void* d_ws, size_t ws_size,
                              hipStream_t stream)
{
    const int*   x    = (const int*)d_in[0];
    const int*   ei   = (const int*)d_in[1];
    const float* ea   = (const float*)d_in[2];
    const float* nemb = (const float*)d_in[3];
    const float* We   = (const float*)d_in[4];
    const float* be   = (const float*)d_in[5];
    const float* eps  = (const float*)d_in[6];
    const float* W1   = (const float*)d_in[7];
    const float* b1   = (const float*)d_in[8];
    const float* g1   = (const float*)d_in[9];
    const float* bb1  = (const float*)d_in[10];
    const float* W2   = (const float*)d_in[11];
    const float* b2   = (const float*)d_in[12];
    const float* g2   = (const float*)d_in[13];
    const float* bb2  = (const float*)d_in[14];
    float* out = (float*)d_out;

    float* ws  = (float*)d_ws;
    float* agg = ws;                 // N*64       = 3,200,000 floats
    float* st1 = ws + 3200000;       // 256 floats (sum[128], sumsq[128])
    float* st2 = ws + 3200256;       // 128 floats (sum[64], sumsq[64])
    float* y1  = ws + 3200384;       // N*128      = 6,400,000 floats
    float* y2  = ws + 9600384;       // N*64       = 3,200,000 floats
    // total: 12,800,384 floats = 51.2 MB

    // zero agg + st1 + st2
    hipMemsetAsync(agg, 0, (size_t)(3200000 + 256 + 128) * sizeof(float), stream);

    for (int l = 0; l < 5; ++l) {
        const int first = (l == 0);
        const float* g2p  = first ? g2  : g2  + (l - 1) * 64;
        const float* bb2p = first ? bb2 : bb2 + (l - 1) * 64;

        edge_kernel<<<2048, 256, 0, stream>>>(
            ei, ea, We + l * 448, be + l * 64,
            x, nemb, y2, st2, g2p, bb2p, agg, first);

        mm1_kernel<<<391, 256, 0, stream>>>(
            agg, x, nemb, y2, st2, g2p, bb2p,
            eps + l, W1 + l * 8192, b1 + l * 128, y1, st1, first);

        // st2 (previous layer's stats) was consumed above; clear for this layer
        hipMemsetAsync(st2, 0, 128 * sizeof(float), stream);

        mm2_kernel<<<782, 256, 0, stream>>>(
            y1, st1, g1 + l * 128, bb1 + l * 128,
            W2 + l * 8192, b2 + l * 64, y2, st2);

        // clear agg + st1 for next layer (contiguous)
        if (l < 4)
            hipMemsetAsync(agg, 0, (size_t)(3200000 + 256) * sizeof(float), stream);
    }

    final_kernel<<<12500, 256, 0, stream>>>(y2, st2, g2 + 4 * 64, bb2 + 4 * 64, out);
}

// Round 2
// 1923.194 us; speedup vs baseline: 1.0161x; 1.0161x over previous
//
#include <hip/hip_runtime.h>
#include <hip/hip_fp16.h>

#define NN 50000
#define EE 800000

// ---------------------------------------------------------------------------
// CSR build: hist -> scan (3 phase) -> scatter packed {src, ea as f16x8}
// ---------------------------------------------------------------------------
__global__ __launch_bounds__(256) void hist_kernel(const int* __restrict__ ei,
                                                   int* __restrict__ deg) {
    const int e = (blockIdx.x << 8) + threadIdx.x;   // 3125*256 == EE
    atomicAdd(&deg[ei[EE + e]], 1);
}

__global__ __launch_bounds__(256) void scanA_kernel(const int* __restrict__ deg,
                                                    int* __restrict__ bsum) {
    __shared__ int sm[256];
    const int t = threadIdx.x;
    const int i = (blockIdx.x << 8) + t;
    sm[t] = (i < NN) ? deg[i] : 0;
    __syncthreads();
    for (int o = 128; o > 0; o >>= 1) {
        if (t < o) sm[t] += sm[t + o];
        __syncthreads();
    }
    if (t == 0) bsum[blockIdx.x] = sm[0];
}

__global__ __launch_bounds__(256) void scanB_kernel(int* __restrict__ bsum) {
    __shared__ int sm[256];
    const int t = threadIdx.x;
    const int v = (t < 196) ? bsum[t] : 0;
    sm[t] = v;
    __syncthreads();
    for (int o = 1; o < 256; o <<= 1) {
        const int u = (t >= o) ? sm[t - o] : 0;
        __syncthreads();
        sm[t] += u;
        __syncthreads();
    }
    bsum[t] = sm[t] - v;   // exclusive scan of block sums
}

__global__ __launch_bounds__(256) void scanC_kernel(const int* __restrict__ deg,
                                                    const int* __restrict__ bsum,
                                                    int* __restrict__ off,
                                                    int* __restrict__ cur) {
    __shared__ int sm[256];
    const int t = threadIdx.x;
    const int i = (blockIdx.x << 8) + t;
    const int v = (i < NN) ? deg[i] : 0;
    sm[t] = v;
    __syncthreads();
    for (int o = 1; o < 256; o <<= 1) {
        const int u = (t >= o) ? sm[t - o] : 0;
        __syncthreads();
        sm[t] += u;
        __syncthreads();
    }
    const int excl = bsum[blockIdx.x] + sm[t] - v;
    if (i < NN) { off[i] = excl; cur[i] = excl; }
    else if (i == NN) off[NN] = excl;
}

__global__ __launch_bounds__(256) void scatter_kernel(const int* __restrict__ ei,
                                                      const float* __restrict__ ea,
                                                      int* __restrict__ cur,
                                                      int* __restrict__ psrc,
                                                      int4* __restrict__ pea) {
    const int e = (blockIdx.x << 8) + threadIdx.x;   // 3125*256 == EE
    const int src = ei[e];
    const int dst = ei[EE + e];
    const float* a = ea + e * 7;
    const unsigned h0 = __half_as_ushort(__float2half(a[0]));
    const unsigned h1 = __half_as_ushort(__float2half(a[1]));
    const unsigned h2 = __half_as_ushort(__float2half(a[2]));
    const unsigned h3 = __half_as_ushort(__float2half(a[3]));
    const unsigned h4 = __half_as_ushort(__float2half(a[4]));
    const unsigned h5 = __half_as_ushort(__float2half(a[5]));
    const unsigned h6 = __half_as_ushort(__float2half(a[6]));
    const int pos = atomicAdd(&cur[dst], 1);
    psrc[pos] = src;
    pea[pos] = make_int4((int)(h0 | (h1 << 16)), (int)(h2 | (h3 << 16)),
                         (int)(h4 | (h5 << 16)), (int)h6);
}

// ---------------------------------------------------------------------------
// Gather: one wave per node. acc_d = sum_e relu(h[src_e][d] + ee_e[d]),
// z[n][d] = (1+eps)*h[n][d] + acc_d.  h = first ? nemb[x] : relu(bn2(y2)).
// Zero atomics; h gathers are coalesced 256B rows (L2/L3 resident).
// ---------------------------------------------------------------------------
__global__ __launch_bounds__(256) void gather_kernel(
    const int* __restrict__ off, const int* __restrict__ psrc,
    const int4* __restrict__ pea,
    const int* __restrict__ x, const float* __restrict__ nemb,
    const float* __restrict__ y2, const float* __restrict__ st2,
    const float* __restrict__ g2p, const float* __restrict__ bb2p,
    const float* __restrict__ We, const float* __restrict__ be,
    const float* __restrict__ epsp,
    float* __restrict__ z, const int first)
{
    const int t = threadIdx.x;
    const int d = t & 63;
    const int n = (blockIdx.x << 2) + (t >> 6);   // 12500*4 == NN

    float scd = 0.f, shd = 0.f;
    if (!first) {
        const float m = st2[d] * (1.0f / NN);
        const float v = fmaxf(st2[64 + d] * (1.0f / NN) - m * m, 0.0f);
        const float r = rsqrtf(v + 1e-5f);
        scd = g2p[d] * r;
        shd = bb2p[d] - m * scd;
    }
    const float bed = be[d];
    const float w0 = We[0 * 64 + d], w1 = We[1 * 64 + d], w2 = We[2 * 64 + d],
                w3 = We[3 * 64 + d], w4 = We[4 * 64 + d], w5 = We[5 * 64 + d],
                w6 = We[6 * 64 + d];

    const int e0 = off[n], e1 = off[n + 1];
    float acc = 0.f;
    for (int e = e0; e < e1; ++e) {
        const int src = psrc[e];
        const int4 pk = pea[e];
        float hs;
        if (first) hs = nemb[(x[src] << 6) + d];
        else       hs = fmaxf(fmaf(y2[(src << 6) + d], scd, shd), 0.f);
        const __half2* hp = reinterpret_cast<const __half2*>(&pk);
        const float2 p01 = __half22float2(hp[0]);
        const float2 p23 = __half22float2(hp[1]);
        const float2 p45 = __half22float2(hp[2]);
        const float2 p67 = __half22float2(hp[3]);
        float ee = bed;
        ee = fmaf(p01.x, w0, ee); ee = fmaf(p01.y, w1, ee);
        ee = fmaf(p23.x, w2, ee); ee = fmaf(p23.y, w3, ee);
        ee = fmaf(p45.x, w4, ee); ee = fmaf(p45.y, w5, ee);
        ee = fmaf(p67.x, w6, ee);
        acc += fmaxf(hs + ee, 0.f);
    }
    float hn;
    if (first) hn = nemb[(x[n] << 6) + d];
    else       hn = fmaxf(fmaf(y2[(n << 6) + d], scd, shd), 0.f);
    z[(n << 6) + d] = fmaf(1.0f + epsp[0], hn, acc);
}

// ---------------------------------------------------------------------------
// MM1: y1 = z @ W1 + b1, stored f16. 64x128 tile, K=64 single stage.
// Thread tile 4 rows (strided 16) x 8 cols. Stats of y1 -> st1.
// NOTE: y1h aliases z byte-for-byte per row (row r = bytes [256r,256r+256)
// in both); each block reads its z rows fully before writing y1 rows.
// ---------------------------------------------------------------------------
__global__ __launch_bounds__(256) void mm1_kernel(
    const float* __restrict__ z, const float* __restrict__ W1,
    const float* __restrict__ b1p, __half* __restrict__ y1h,
    float* __restrict__ st1)
{
    __shared__ float As[64][68];    // pad 68: 2-way bank alias (free), 16B-aligned rows
    __shared__ float Bs[64][128];
    const int t = threadIdx.x;
    const int r0 = blockIdx.x << 6;
    const int rowg = t & 15, colg = t >> 4;
    const int cbase = colg << 3;

    for (int i = t; i < 1024; i += 256) {       // A: 64 rows x 16 float4
        const int row = i >> 4, c4 = (i & 15) << 2;
        const int r = r0 + row;
        float4 v = make_float4(0.f, 0.f, 0.f, 0.f);
        if (r < NN) v = ((const float4*)z)[(r << 4) + (i & 15)];
        *(float4*)&As[row][c4] = v;
    }
    for (int i = t; i < 2048; i += 256) {       // B: 64x128 = 2048 float4
        ((float4*)&Bs[i >> 5][0])[i & 31] = ((const float4*)W1)[i];
    }
    __syncthreads();

    float acc[4][8];
#pragma unroll
    for (int j = 0; j < 4; ++j)
#pragma unroll
        for (int c = 0; c < 8; ++c) acc[j][c] = 0.f;

#pragma unroll 4
    for (int k = 0; k < 64; ++k) {
        float a[4];
#pragma unroll
        for (int j = 0; j < 4; ++j) a[j] = As[rowg + (j << 4)][k];
        const float4 b0 = *(const float4*)&Bs[k][cbase];
        const float4 b1v = *(const float4*)&Bs[k][cbase + 4];
        const float b[8] = {b0.x, b0.y, b0.z, b0.w, b1v.x, b1v.y, b1v.z, b1v.w};
#pragma unroll
        for (int j = 0; j < 4; ++j)
#pragma unroll
            for (int c = 0; c < 8; ++c)
                acc[j][c] = fmaf(a[j], b[c], acc[j][c]);
    }

    float bv[8];
#pragma unroll
    for (int c = 0; c < 8; ++c) bv[c] = b1p[cbase + c];
    float s[8], sq[8];
#pragma unroll
    for (int c = 0; c < 8; ++c) { s[c] = 0.f; sq[c] = 0.f; }
#pragma unroll
    for (int j = 0; j < 4; ++j) {
        const int r = r0 + rowg + (j << 4);
        if (r < NN) {
            float y[8];
#pragma unroll
            for (int c = 0; c < 8; ++c) y[c] = acc[j][c] + bv[c];
            unsigned u0 = __half_as_ushort(__float2half(y[0])) |
                          ((unsigned)__half_as_ushort(__float2half(y[1])) << 16);
            unsigned u1 = __half_as_ushort(__float2half(y[2])) |
                          ((unsigned)__half_as_ushort(__float2half(y[3])) << 16);
            unsigned u2 = __half_as_ushort(__float2half(y[4])) |
                          ((unsigned)__half_as_ushort(__float2half(y[5])) << 16);
            unsigned u3 = __half_as_ushort(__float2half(y[6])) |
                          ((unsigned)__half_as_ushort(__float2half(y[7])) << 16);
            *(int4*)(y1h + ((size_t)r << 7) + cbase) =
                make_int4((int)u0, (int)u1, (int)u2, (int)u3);
#pragma unroll
            for (int c = 0; c < 8; ++c) { s[c] += y[c]; sq[c] += y[c] * y[c]; }
        }
    }
#pragma unroll
    for (int c = 0; c < 8; ++c) {
#pragma unroll
        for (int o = 8; o > 0; o >>= 1) {
            s[c] += __shfl_down(s[c], o, 16);
            sq[c] += __shfl_down(sq[c], o, 16);
        }
    }
    if (rowg == 0) {
#pragma unroll
        for (int c = 0; c < 8; ++c) {
            atomicAdd(&st1[cbase + c], s[c]);
            atomicAdd(&st1[128 + cbase + c], sq[c]);
        }
    }
}

// ---------------------------------------------------------------------------
// MM2: y2 = relu(bn1(y1)) @ W2 + b2. 64x64 tile, K=128 single stage.
// Thread tile 4 rows (strided 16) x 4 cols. Stats of y2 -> st2.
// ---------------------------------------------------------------------------
__global__ __launch_bounds__(256) void mm2_kernel(
    const __half* __restrict__ y1h, const float* __restrict__ st1,
    const float* __restrict__ g1, const float* __restrict__ bb1,
    const float* __restrict__ W2, const float* __restrict__ b2,
    float* __restrict__ y2, float* __restrict__ st2)
{
    __shared__ float As[64][132];   // pad 132: 2-way bank alias (free), 16B-aligned rows
    __shared__ float Bs[128][64];
    __shared__ float sc1[128], sh1[128];
    const int t = threadIdx.x;
    const int r0 = blockIdx.x << 6;
    const int rowg = t & 15, colg = t >> 4;
    const int cbase = colg << 2;

    if (t < 128) {
        const float m = st1[t] * (1.0f / NN);
        const float v = fmaxf(st1[128 + t] * (1.0f / NN) - m * m, 0.0f);
        const float r = rsqrtf(v + 1e-5f);
        const float sc = g1[t] * r;
        sc1[t] = sc; sh1[t] = bb1[t] - m * sc;
    }
    __syncthreads();

    for (int i = t; i < 1024; i += 256) {       // A: 64 rows x 16 half8
        const int row = i >> 4, h8 = i & 15;
        const int r = r0 + row;
        const int k0 = h8 << 3;
        float v[8] = {0.f, 0.f, 0.f, 0.f, 0.f, 0.f, 0.f, 0.f};
        if (r < NN) {
            const int4 pk = *(const int4*)(y1h + ((size_t)r << 7) + k0);
            const __half2* hp = reinterpret_cast<const __half2*>(&pk);
            const float2 f0 = __half22float2(hp[0]);
            const float2 f1 = __half22float2(hp[1]);
            const float2 f2 = __half22float2(hp[2]);
            const float2 f3 = __half22float2(hp[3]);
            const float u[8] = {f0.x, f0.y, f1.x, f1.y, f2.x, f2.y, f3.x, f3.y};
#pragma unroll
            for (int c = 0; c < 8; ++c)
                v[c] = fmaxf(fmaf(u[c], sc1[k0 + c], sh1[k0 + c]), 0.f);
        }
        *(float4*)&As[row][k0] = make_float4(v[0], v[1], v[2], v[3]);
        *(float4*)&As[row][k0 + 4] = make_float4(v[4], v[5], v[6], v[7]);
    }
    for (int i = t; i < 2048; i += 256) {       // B: 128x64 = 2048 float4
        ((float4*)&Bs[i >> 4][0])[i & 15] = ((const float4*)W2)[i];
    }
    __syncthreads();

    float acc[4][4];
#pragma unroll
    for (int j = 0; j < 4; ++j)
#pragma unroll
        for (int c = 0; c < 4; ++c) acc[j][c] = 0.f;

#pragma unroll 4
    for (int k = 0; k < 128; ++k) {
        float a[4];
#pragma unroll
        for (int j = 0; j < 4; ++j) a[j] = As[rowg + (j << 4)][k];
        const float4 b4 = *(const float4*)&Bs[k][cbase];
        const float b[4] = {b4.x, b4.y, b4.z, b4.w};
#pragma unroll
        for (int j = 0; j < 4; ++j)
#pragma unroll
            for (int c = 0; c < 4; ++c)
                acc[j][c] = fmaf(a[j], b[c], acc[j][c]);
    }

    float b2v[4];
#pragma unroll
    for (int c = 0; c < 4; ++c) b2v[c] = b2[cbase + c];
    float s[4], sq[4];
#pragma unroll
    for (int c = 0; c < 4; ++c) { s[c] = 0.f; sq[c] = 0.f; }
#pragma unroll
    for (int j = 0; j < 4; ++j) {
        const int r = r0 + rowg + (j << 4);
        if (r < NN) {
            float y[4];
#pragma unroll
            for (int c = 0; c < 4; ++c) y[c] = acc[j][c] + b2v[c];
            *(float4*)&y2[((size_t)r << 6) + cbase] = make_float4(y[0], y[1], y[2], y[3]);
#pragma unroll
            for (int c = 0; c < 4; ++c) { s[c] += y[c]; sq[c] += y[c] * y[c]; }
        }
    }
#pragma unroll
    for (int c = 0; c < 4; ++c) {
#pragma unroll
        for (int o = 8; o > 0; o >>= 1) {
            s[c] += __shfl_down(s[c], o, 16);
            sq[c] += __shfl_down(sq[c], o, 16);
        }
    }
    if (rowg == 0) {
#pragma unroll
        for (int c = 0; c < 4; ++c) {
            atomicAdd(&st2[cbase + c], s[c]);
            atomicAdd(&st2[64 + cbase + c], sq[c]);
        }
    }
}

// ---------------------------------------------------------------------------
// Final: out = bn2(y2) of layer 4 (no relu on last layer).
// ---------------------------------------------------------------------------
__global__ __launch_bounds__(256) void final_kernel(
    const float* __restrict__ y2, const float* __restrict__ st2,
    const float* __restrict__ g2, const float* __restrict__ bb2,
    float* __restrict__ out)
{
    const int i = (blockIdx.x << 8) + threadIdx.x;
    if (i >= NN * 64) return;
    const int d = i & 63;
    const float m = st2[d] * (1.0f / NN);
    const float v = fmaxf(st2[64 + d] * (1.0f / NN) - m * m, 0.0f);
    const float r = rsqrtf(v + 1e-5f);
    const float sc = g2[d] * r;
    const float sh = bb2[d] - m * sc;
    out[i] = y2[i] * sc + sh;
}

extern "C" void kernel_launch(void* const* d_in, const int* in_sizes, int n_in,
                              void* d_out, int out_size, void* d_ws, size_t ws_size,
                              hipStream_t stream)
{
    const int*   x    = (const int*)d_in[0];
    const int*   ei   = (const int*)d_in[1];
    const float* ea   = (const float*)d_in[2];
    const float* nemb = (const float*)d_in[3];
    const float* We   = (const float*)d_in[4];
    const float* be   = (const float*)d_in[5];
    const float* eps  = (const float*)d_in[6];
    const float* W1   = (const float*)d_in[7];
    const float* b1   = (const float*)d_in[8];
    const float* g1   = (const float*)d_in[9];
    const float* bb1  = (const float*)d_in[10];
    const float* W2   = (const float*)d_in[11];
    const float* b2   = (const float*)d_in[12];
    const float* g2   = (const float*)d_in[13];
    const float* bb2  = (const float*)d_in[14];
    float* out = (float*)d_out;

    // workspace layout (4-byte word offsets); total 10,550,784 words = 42.2 MB
    int*   iws  = (int*)d_ws;
    float* fws  = (float*)d_ws;
    int*   off  = iws + 0;          // 50001
    int*   deg  = iws + 50048;      // 50000
    int*   cur  = iws + 100096;     // 50000
    int*   bsum = iws + 150144;     // 256
    float* st1  = fws + 150400;     // 256 (sum128 + sumsq128)
    float* st2  = fws + 150656;     // 128 (sum64 + sumsq64)
    int*   psrc = iws + 150784;     // 800000
    int4*  pea  = (int4*)(iws + 950784);   // 800000 x 16B
    float* z    = fws + 4150784;    // 50000 x 64 f32   } same bytes,
    __half* y1h = (__half*)(fws + 4150784); // 50000x128 } row-aliased
    float* y2   = fws + 7350784;    // 50000 x 64 f32

    hipMemsetAsync(deg, 0, 50000 * sizeof(int), stream);
    hipMemsetAsync(st1, 0, 384 * sizeof(float), stream);   // st1+st2 contiguous

    hist_kernel   <<<3125, 256, 0, stream>>>(ei, deg);
    scanA_kernel  <<<196,  256, 0, stream>>>(deg, bsum);
    scanB_kernel  <<<1,    256, 0, stream>>>(bsum);
    scanC_kernel  <<<196,  256, 0, stream>>>(deg, bsum, off, cur);
    scatter_kernel<<<3125, 256, 0, stream>>>(ei, ea, cur, psrc, pea);

    for (int l = 0; l < 5; ++l) {
        const int first = (l == 0);
        const float* g2p  = g2  + (first ? 0 : (l - 1) * 64);
        const float* bb2p = bb2 + (first ? 0 : (l - 1) * 64);

        gather_kernel<<<12500, 256, 0, stream>>>(
            off, psrc, pea, x, nemb, y2, st2, g2p, bb2p,
            We + l * 448, be + l * 64, eps + l, z, first);

        mm1_kernel<<<782, 256, 0, stream>>>(z, W1 + l * 8192, b1 + l * 128, y1h, st1);

        hipMemsetAsync(st2, 0, 128 * sizeof(float), stream);   // after gather consumed it

        mm2_kernel<<<782, 256, 0, stream>>>(y1h, st1, g1 + l * 128, bb1 + l * 128,
                                            W2 + l * 8192, b2 + l * 64, y2, st2);

        if (l < 4) hipMemsetAsync(st1, 0, 256 * sizeof(float), stream);
    }

    final_kernel<<<12500, 256, 0, stream>>>(y2, st2, g2 + 256, bb2 + 256, out);
}

// Round 3
// 897.973 us; speedup vs baseline: 2.1761x; 2.1417x over previous
//
#include <hip/hip_runtime.h>
#include <hip/hip_fp16.h>

#define NN 50000
#define EE 800000
#define NB 782   // blocks in mm1/mm2 grids

// ---------------------------------------------------------------------------
// CSR build: hist -> scan (3 phase) -> scatter packed {src, ea as f16x8}
// ---------------------------------------------------------------------------
__global__ __launch_bounds__(256) void hist_kernel(const int* __restrict__ ei,
                                                   int* __restrict__ deg) {
    const int e = (blockIdx.x << 8) + threadIdx.x;   // 3125*256 == EE
    atomicAdd(&deg[ei[EE + e]], 1);
}

__global__ __launch_bounds__(256) void scanA_kernel(const int* __restrict__ deg,
                                                    int* __restrict__ bsum) {
    __shared__ int sm[256];
    const int t = threadIdx.x;
    const int i = (blockIdx.x << 8) + t;
    sm[t] = (i < NN) ? deg[i] : 0;
    __syncthreads();
    for (int o = 128; o > 0; o >>= 1) {
        if (t < o) sm[t] += sm[t + o];
        __syncthreads();
    }
    if (t == 0) bsum[blockIdx.x] = sm[0];
}

__global__ __launch_bounds__(256) void scanB_kernel(int* __restrict__ bsum) {
    __shared__ int sm[256];
    const int t = threadIdx.x;
    const int v = (t < 196) ? bsum[t] : 0;
    sm[t] = v;
    __syncthreads();
    for (int o = 1; o < 256; o <<= 1) {
        const int u = (t >= o) ? sm[t - o] : 0;
        __syncthreads();
        sm[t] += u;
        __syncthreads();
    }
    bsum[t] = sm[t] - v;   // exclusive scan of block sums
}

__global__ __launch_bounds__(256) void scanC_kernel(const int* __restrict__ deg,
                                                    const int* __restrict__ bsum,
                                                    int* __restrict__ off,
                                                    int* __restrict__ cur) {
    __shared__ int sm[256];
    const int t = threadIdx.x;
    const int i = (blockIdx.x << 8) + t;
    const int v = (i < NN) ? deg[i] : 0;
    sm[t] = v;
    __syncthreads();
    for (int o = 1; o < 256; o <<= 1) {
        const int u = (t >= o) ? sm[t - o] : 0;
        __syncthreads();
        sm[t] += u;
        __syncthreads();
    }
    const int excl = bsum[blockIdx.x] + sm[t] - v;
    if (i < NN) { off[i] = excl; cur[i] = excl; }
    else if (i == NN) off[NN] = excl;
}

__global__ __launch_bounds__(256) void scatter_kernel(const int* __restrict__ ei,
                                                      const float* __restrict__ ea,
                                                      int* __restrict__ cur,
                                                      int* __restrict__ psrc,
                                                      int4* __restrict__ pea) {
    const int e = (blockIdx.x << 8) + threadIdx.x;   // 3125*256 == EE
    const int src = ei[e];
    const int dst = ei[EE + e];
    const float* a = ea + e * 7;
    const unsigned h0 = __half_as_ushort(__float2half(a[0]));
    const unsigned h1 = __half_as_ushort(__float2half(a[1]));
    const unsigned h2 = __half_as_ushort(__float2half(a[2]));
    const unsigned h3 = __half_as_ushort(__float2half(a[3]));
    const unsigned h4 = __half_as_ushort(__float2half(a[4]));
    const unsigned h5 = __half_as_ushort(__float2half(a[5]));
    const unsigned h6 = __half_as_ushort(__float2half(a[6]));
    const int pos = atomicAdd(&cur[dst], 1);
    psrc[pos] = src;
    pea[pos] = make_int4((int)(h0 | (h1 << 16)), (int)(h2 | (h3 << 16)),
                         (int)(h4 | (h5 << 16)), (int)h6);
}

// ---------------------------------------------------------------------------
// BN stats reduce: one block per column c in [0, half). Sums part[c][0..nb)
// and part[half+c][0..nb), emits scsh[c]=scale, scsh[half+c]=shift.
// part layout is transposed (column-major): coalesced reads here; producers
// do scattered 4B stores (no RMW serialization — that was R2's 169us bug).
// ---------------------------------------------------------------------------
__global__ __launch_bounds__(256) void bnstats_kernel(
    const float* __restrict__ part, const int nb, const int half,
    const float* __restrict__ g, const float* __restrict__ bb,
    float* __restrict__ scsh)
{
    __shared__ float ss[256], qq[256];
    const int c = blockIdx.x, t = threadIdx.x;
    float s = 0.f, q = 0.f;
    for (int b = t; b < nb; b += 256) {
        s += part[c * nb + b];
        q += part[(half + c) * nb + b];
    }
    ss[t] = s; qq[t] = q;
    __syncthreads();
    for (int o = 128; o > 0; o >>= 1) {
        if (t < o) { ss[t] += ss[t + o]; qq[t] += qq[t + o]; }
        __syncthreads();
    }
    if (t == 0) {
        const float m = ss[0] * (1.0f / NN);
        const float v = fmaxf(qq[0] * (1.0f / NN) - m * m, 0.0f);
        const float sc = g[c] * rsqrtf(v + 1e-5f);
        scsh[c] = sc;
        scsh[half + c] = bb[c] - m * sc;
    }
}

// ---------------------------------------------------------------------------
// Gather: one wave per node. acc_d = sum_e relu(h[src_e][d] + ee_e[d]),
// z[n][d] = (1+eps)*h[n][d] + acc_d.  h = first ? nemb[x] : relu(bn2(y2)).
// ---------------------------------------------------------------------------
__global__ __launch_bounds__(256) void gather_kernel(
    const int* __restrict__ off, const int* __restrict__ psrc,
    const int4* __restrict__ pea,
    const int* __restrict__ x, const float* __restrict__ nemb,
    const float* __restrict__ y2, const float* __restrict__ scsh2,
    const float* __restrict__ We, const float* __restrict__ be,
    const float* __restrict__ epsp,
    float* __restrict__ z, const int first)
{
    const int t = threadIdx.x;
    const int d = t & 63;
    const int n = (blockIdx.x << 2) + (t >> 6);   // 12500*4 == NN

    float scd = 0.f, shd = 0.f;
    if (!first) { scd = scsh2[d]; shd = scsh2[64 + d]; }
    const float bed = be[d];
    const float w0 = We[0 * 64 + d], w1 = We[1 * 64 + d], w2 = We[2 * 64 + d],
                w3 = We[3 * 64 + d], w4 = We[4 * 64 + d], w5 = We[5 * 64 + d],
                w6 = We[6 * 64 + d];

    const int e0 = off[n], e1 = off[n + 1];
    float acc = 0.f;
    for (int e = e0; e < e1; ++e) {
        const int src = psrc[e];
        const int4 pk = pea[e];
        float hs;
        if (first) hs = nemb[(x[src] << 6) + d];
        else       hs = fmaxf(fmaf(y2[(src << 6) + d], scd, shd), 0.f);
        const __half2* hp = reinterpret_cast<const __half2*>(&pk);
        const float2 p01 = __half22float2(hp[0]);
        const float2 p23 = __half22float2(hp[1]);
        const float2 p45 = __half22float2(hp[2]);
        const float2 p67 = __half22float2(hp[3]);
        float ee = bed;
        ee = fmaf(p01.x, w0, ee); ee = fmaf(p01.y, w1, ee);
        ee = fmaf(p23.x, w2, ee); ee = fmaf(p23.y, w3, ee);
        ee = fmaf(p45.x, w4, ee); ee = fmaf(p45.y, w5, ee);
        ee = fmaf(p67.x, w6, ee);
        acc += fmaxf(hs + ee, 0.f);
    }
    float hn;
    if (first) hn = nemb[(x[n] << 6) + d];
    else       hn = fmaxf(fmaf(y2[(n << 6) + d], scd, shd), 0.f);
    z[(n << 6) + d] = fmaf(1.0f + epsp[0], hn, acc);
}

// ---------------------------------------------------------------------------
// MM1: y1 = z @ W1 + b1, stored f16. 64x128 tile, K=64 single stage.
// Per-column partial sums/sumsq -> part1[c][bid] (transposed, no atomics).
// y1h aliases z byte-for-byte per row; block reads its z rows before writing.
// ---------------------------------------------------------------------------
__global__ __launch_bounds__(256) void mm1_kernel(
    const float* __restrict__ z, const float* __restrict__ W1,
    const float* __restrict__ b1p, __half* __restrict__ y1h,
    float* __restrict__ part1)
{
    __shared__ float As[64][68];
    __shared__ float Bs[64][128];
    const int t = threadIdx.x;
    const int r0 = blockIdx.x << 6;
    const int rowg = t & 15, colg = t >> 4;
    const int cbase = colg << 3;

    for (int i = t; i < 1024; i += 256) {       // A: 64 rows x 16 float4
        const int row = i >> 4, c4 = (i & 15) << 2;
        const int r = r0 + row;
        float4 v = make_float4(0.f, 0.f, 0.f, 0.f);
        if (r < NN) v = ((const float4*)z)[(r << 4) + (i & 15)];
        *(float4*)&As[row][c4] = v;
    }
    for (int i = t; i < 2048; i += 256) {       // B: 64x128 = 2048 float4
        ((float4*)&Bs[i >> 5][0])[i & 31] = ((const float4*)W1)[i];
    }
    __syncthreads();

    float acc[4][8];
#pragma unroll
    for (int j = 0; j < 4; ++j)
#pragma unroll
        for (int c = 0; c < 8; ++c) acc[j][c] = 0.f;

#pragma unroll 4
    for (int k = 0; k < 64; ++k) {
        float a[4];
#pragma unroll
        for (int j = 0; j < 4; ++j) a[j] = As[rowg + (j << 4)][k];
        const float4 b0 = *(const float4*)&Bs[k][cbase];
        const float4 b1v = *(const float4*)&Bs[k][cbase + 4];
        const float b[8] = {b0.x, b0.y, b0.z, b0.w, b1v.x, b1v.y, b1v.z, b1v.w};
#pragma unroll
        for (int j = 0; j < 4; ++j)
#pragma unroll
            for (int c = 0; c < 8; ++c)
                acc[j][c] = fmaf(a[j], b[c], acc[j][c]);
    }

    float bv[8];
#pragma unroll
    for (int c = 0; c < 8; ++c) bv[c] = b1p[cbase + c];
    float s[8], sq[8];
#pragma unroll
    for (int c = 0; c < 8; ++c) { s[c] = 0.f; sq[c] = 0.f; }
#pragma unroll
    for (int j = 0; j < 4; ++j) {
        const int r = r0 + rowg + (j << 4);
        if (r < NN) {
            float y[8];
#pragma unroll
            for (int c = 0; c < 8; ++c) y[c] = acc[j][c] + bv[c];
            unsigned u0 = __half_as_ushort(__float2half(y[0])) |
                          ((unsigned)__half_as_ushort(__float2half(y[1])) << 16);
            unsigned u1 = __half_as_ushort(__float2half(y[2])) |
                          ((unsigned)__half_as_ushort(__float2half(y[3])) << 16);
            unsigned u2 = __half_as_ushort(__float2half(y[4])) |
                          ((unsigned)__half_as_ushort(__float2half(y[5])) << 16);
            unsigned u3 = __half_as_ushort(__float2half(y[6])) |
                          ((unsigned)__half_as_ushort(__float2half(y[7])) << 16);
            *(int4*)(y1h + ((size_t)r << 7) + cbase) =
                make_int4((int)u0, (int)u1, (int)u2, (int)u3);
#pragma unroll
            for (int c = 0; c < 8; ++c) { s[c] += y[c]; sq[c] += y[c] * y[c]; }
        }
    }
#pragma unroll
    for (int c = 0; c < 8; ++c) {
#pragma unroll
        for (int o = 8; o > 0; o >>= 1) {
            s[c] += __shfl_down(s[c], o, 16);
            sq[c] += __shfl_down(sq[c], o, 16);
        }
    }
    if (rowg == 0) {
        const int bid = blockIdx.x;
#pragma unroll
        for (int c = 0; c < 8; ++c) {
            part1[(cbase + c) * NB + bid] = s[c];
            part1[(128 + cbase + c) * NB + bid] = sq[c];
        }
    }
}

// ---------------------------------------------------------------------------
// MM2: y2 = relu(bn1(y1)) @ W2 + b2. 64x64 tile, K=128 single stage.
// Per-column partials -> part2[c][bid] (transposed, no atomics).
// ---------------------------------------------------------------------------
__global__ __launch_bounds__(256) void mm2_kernel(
    const __half* __restrict__ y1h, const float* __restrict__ scsh1,
    const float* __restrict__ W2, const float* __restrict__ b2,
    float* __restrict__ y2, float* __restrict__ part2)
{
    __shared__ float As[64][132];
    __shared__ float Bs[128][64];
    __shared__ float sc1[128], sh1[128];
    const int t = threadIdx.x;
    const int r0 = blockIdx.x << 6;
    const int rowg = t & 15, colg = t >> 4;
    const int cbase = colg << 2;

    if (t < 128) { sc1[t] = scsh1[t]; sh1[t] = scsh1[128 + t]; }
    __syncthreads();

    for (int i = t; i < 1024; i += 256) {       // A: 64 rows x 16 half8
        const int row = i >> 4, h8 = i & 15;
        const int r = r0 + row;
        const int k0 = h8 << 3;
        float v[8] = {0.f, 0.f, 0.f, 0.f, 0.f, 0.f, 0.f, 0.f};
        if (r < NN) {
            const int4 pk = *(const int4*)(y1h + ((size_t)r << 7) + k0);
            const __half2* hp = reinterpret_cast<const __half2*>(&pk);
            const float2 f0 = __half22float2(hp[0]);
            const float2 f1 = __half22float2(hp[1]);
            const float2 f2 = __half22float2(hp[2]);
            const float2 f3 = __half22float2(hp[3]);
            const float u[8] = {f0.x, f0.y, f1.x, f1.y, f2.x, f2.y, f3.x, f3.y};
#pragma unroll
            for (int c = 0; c < 8; ++c)
                v[c] = fmaxf(fmaf(u[c], sc1[k0 + c], sh1[k0 + c]), 0.f);
        }
        *(float4*)&As[row][k0] = make_float4(v[0], v[1], v[2], v[3]);
        *(float4*)&As[row][k0 + 4] = make_float4(v[4], v[5], v[6], v[7]);
    }
    for (int i = t; i < 2048; i += 256) {       // B: 128x64 = 2048 float4
        ((float4*)&Bs[i >> 4][0])[i & 15] = ((const float4*)W2)[i];
    }
    __syncthreads();

    float acc[4][4];
#pragma unroll
    for (int j = 0; j < 4; ++j)
#pragma unroll
        for (int c = 0; c < 4; ++c) acc[j][c] = 0.f;

#pragma unroll 4
    for (int k = 0; k < 128; ++k) {
        float a[4];
#pragma unroll
        for (int j = 0; j < 4; ++j) a[j] = As[rowg + (j << 4)][k];
        const float4 b4 = *(const float4*)&Bs[k][cbase];
        const float b[4] = {b4.x, b4.y, b4.z, b4.w};
#pragma unroll
        for (int j = 0; j < 4; ++j)
#pragma unroll
            for (int c = 0; c < 4; ++c)
                acc[j][c] = fmaf(a[j], b[c], acc[j][c]);
    }

    float b2v[4];
#pragma unroll
    for (int c = 0; c < 4; ++c) b2v[c] = b2[cbase + c];
    float s[4], sq[4];
#pragma unroll
    for (int c = 0; c < 4; ++c) { s[c] = 0.f; sq[c] = 0.f; }
#pragma unroll
    for (int j = 0; j < 4; ++j) {
        const int r = r0 + rowg + (j << 4);
        if (r < NN) {
            float y[4];
#pragma unroll
            for (int c = 0; c < 4; ++c) y[c] = acc[j][c] + b2v[c];
            *(float4*)&y2[((size_t)r << 6) + cbase] = make_float4(y[0], y[1], y[2], y[3]);
#pragma unroll
            for (int c = 0; c < 4; ++c) { s[c] += y[c]; sq[c] += y[c] * y[c]; }
        }
    }
#pragma unroll
    for (int c = 0; c < 4; ++c) {
#pragma unroll
        for (int o = 8; o > 0; o >>= 1) {
            s[c] += __shfl_down(s[c], o, 16);
            sq[c] += __shfl_down(sq[c], o, 16);
        }
    }
    if (rowg == 0) {
        const int bid = blockIdx.x;
#pragma unroll
        for (int c = 0; c < 4; ++c) {
            part2[(cbase + c) * NB + bid] = s[c];
            part2[(64 + cbase + c) * NB + bid] = sq[c];
        }
    }
}

// ---------------------------------------------------------------------------
// Final: out = bn2(y2) of layer 4 (no relu on last layer).
// ---------------------------------------------------------------------------
__global__ __launch_bounds__(256) void final_kernel(
    const float* __restrict__ y2, const float* __restrict__ scsh2,
    float* __restrict__ out)
{
    const int i = (blockIdx.x << 8) + threadIdx.x;
    if (i >= NN * 64) return;
    const int d = i & 63;
    out[i] = fmaf(y2[i], scsh2[d], scsh2[64 + d]);
}

extern "C" void kernel_launch(void* const* d_in, const int* in_sizes, int n_in,
                              void* d_out, int out_size, void* d_ws, size_t ws_size,
                              hipStream_t stream)
{
    const int*   x    = (const int*)d_in[0];
    const int*   ei   = (const int*)d_in[1];
    const float* ea   = (const float*)d_in[2];
    const float* nemb = (const float*)d_in[3];
    const float* We   = (const float*)d_in[4];
    const float* be   = (const float*)d_in[5];
    const float* eps  = (const float*)d_in[6];
    const float* W1   = (const float*)d_in[7];
    const float* b1   = (const float*)d_in[8];
    const float* g1   = (const float*)d_in[9];
    const float* bb1  = (const float*)d_in[10];
    const float* W2   = (const float*)d_in[11];
    const float* b2   = (const float*)d_in[12];
    const float* g2   = (const float*)d_in[13];
    const float* bb2  = (const float*)d_in[14];
    float* out = (float*)d_out;

    // workspace layout (4-byte word offsets); total 10,851,072 words = 43.4 MB
    int*   iws   = (int*)d_ws;
    float* fws   = (float*)d_ws;
    int*   off   = iws + 0;          // 50001
    int*   deg   = iws + 50048;      // 50000
    int*   cur   = iws + 100096;     // 50000
    int*   bsum  = iws + 150144;     // 256
    float* scsh1 = fws + 150400;     // 256 (sc128, sh128)
    float* scsh2 = fws + 150656;     // 128 (sc64, sh64)
    float* part1 = fws + 150784;     // 256*782 = 200192
    float* part2 = fws + 350976;     // 128*782 = 100096
    int*   psrc  = iws + 451072;     // 800000
    int4*  pea   = (int4*)(iws + 1251072);  // 800000 x 16B
    float* z     = fws + 4451072;    // 50000 x 64 f32   } same bytes,
    __half* y1h  = (__half*)(fws + 4451072);// 50000x128  } row-aliased
    float* y2    = fws + 7651072;    // 50000 x 64 f32

    hipMemsetAsync(deg, 0, 50000 * sizeof(int), stream);

    hist_kernel   <<<3125, 256, 0, stream>>>(ei, deg);
    scanA_kernel  <<<196,  256, 0, stream>>>(deg, bsum);
    scanB_kernel  <<<1,    256, 0, stream>>>(bsum);
    scanC_kernel  <<<196,  256, 0, stream>>>(deg, bsum, off, cur);
    scatter_kernel<<<3125, 256, 0, stream>>>(ei, ea, cur, psrc, pea);

    for (int l = 0; l < 5; ++l) {
        const int first = (l == 0);

        gather_kernel<<<12500, 256, 0, stream>>>(
            off, psrc, pea, x, nemb, y2, scsh2,
            We + l * 448, be + l * 64, eps + l, z, first);

        mm1_kernel<<<NB, 256, 0, stream>>>(z, W1 + l * 8192, b1 + l * 128, y1h, part1);

        bnstats_kernel<<<128, 256, 0, stream>>>(part1, NB, 128,
                                                g1 + l * 128, bb1 + l * 128, scsh1);

        mm2_kernel<<<NB, 256, 0, stream>>>(y1h, scsh1, W2 + l * 8192, b2 + l * 64,
                                           y2, part2);

        bnstats_kernel<<<64, 256, 0, stream>>>(part2, NB, 64,
                                               g2 + l * 64, bb2 + l * 64, scsh2);
    }

    final_kernel<<<12500, 256, 0, stream>>>(y2, scsh2, out);
}

// Round 5
// 667.623 us; speedup vs baseline: 2.9270x; 1.3450x over previous
//
#include <hip/hip_runtime.h>
#include <hip/hip_fp16.h>

#define NN 50000
#define EE 800000
#define NB 782   // blocks in mm1/mm2 grids

// bit-cast helpers (no __half2_as_uint in HIP)
__device__ __forceinline__ unsigned h2u(__half2 h) {
    union { __half2 h; unsigned u; } c; c.h = h; return c.u;
}

// ---------------------------------------------------------------------------
// CSR build: hist -> scan (3 phase) -> scatter packed {ea f16 x7, src u16}
// ---------------------------------------------------------------------------
__global__ __launch_bounds__(256) void hist_kernel(const int* __restrict__ ei,
                                                   int* __restrict__ deg) {
    const int e = (blockIdx.x << 8) + threadIdx.x;   // 3125*256 == EE
    atomicAdd(&deg[ei[EE + e]], 1);
}

__global__ __launch_bounds__(256) void scanA_kernel(const int* __restrict__ deg,
                                                    int* __restrict__ bsum) {
    __shared__ int sm[256];
    const int t = threadIdx.x;
    const int i = (blockIdx.x << 8) + t;
    sm[t] = (i < NN) ? deg[i] : 0;
    __syncthreads();
    for (int o = 128; o > 0; o >>= 1) {
        if (t < o) sm[t] += sm[t + o];
        __syncthreads();
    }
    if (t == 0) bsum[blockIdx.x] = sm[0];
}

__global__ __launch_bounds__(256) void scanB_kernel(int* __restrict__ bsum) {
    __shared__ int sm[256];
    const int t = threadIdx.x;
    const int v = (t < 196) ? bsum[t] : 0;
    sm[t] = v;
    __syncthreads();
    for (int o = 1; o < 256; o <<= 1) {
        const int u = (t >= o) ? sm[t - o] : 0;
        __syncthreads();
        sm[t] += u;
        __syncthreads();
    }
    bsum[t] = sm[t] - v;   // exclusive scan of block sums
}

__global__ __launch_bounds__(256) void scanC_kernel(const int* __restrict__ deg,
                                                    const int* __restrict__ bsum,
                                                    int* __restrict__ off,
                                                    int* __restrict__ cur) {
    __shared__ int sm[256];
    const int t = threadIdx.x;
    const int i = (blockIdx.x << 8) + t;
    const int v = (i < NN) ? deg[i] : 0;
    sm[t] = v;
    __syncthreads();
    for (int o = 1; o < 256; o <<= 1) {
        const int u = (t >= o) ? sm[t - o] : 0;
        __syncthreads();
        sm[t] += u;
        __syncthreads();
    }
    const int excl = bsum[blockIdx.x] + sm[t] - v;
    if (i < NN) { off[i] = excl; cur[i] = excl; }
    else if (i == NN) off[NN] = excl;
}

__global__ __launch_bounds__(256) void scatter_kernel(const int* __restrict__ ei,
                                                      const float* __restrict__ ea,
                                                      int* __restrict__ cur,
                                                      int4* __restrict__ pea) {
    const int e = (blockIdx.x << 8) + threadIdx.x;   // 3125*256 == EE
    const int src = ei[e];          // < 50000 < 2^16: packed into w high bits
    const int dst = ei[EE + e];
    const float* a = ea + e * 7;
    const unsigned h0 = __half_as_ushort(__float2half(a[0]));
    const unsigned h1 = __half_as_ushort(__float2half(a[1]));
    const unsigned h2 = __half_as_ushort(__float2half(a[2]));
    const unsigned h3 = __half_as_ushort(__float2half(a[3]));
    const unsigned h4 = __half_as_ushort(__float2half(a[4]));
    const unsigned h5 = __half_as_ushort(__float2half(a[5]));
    const unsigned h6 = __half_as_ushort(__float2half(a[6]));
    const int pos = atomicAdd(&cur[dst], 1);
    pea[pos] = make_int4((int)(h0 | (h1 << 16)), (int)(h2 | (h3 << 16)),
                         (int)(h4 | (h5 << 16)), (int)(h6 | ((unsigned)src << 16)));
}

// ---------------------------------------------------------------------------
// BN stats reduce: one block per column c in [0, half). Transposed partials
// (no contended atomics — that was R2's 169us bug). Emits scale/shift.
// ---------------------------------------------------------------------------
__global__ __launch_bounds__(256) void bnstats_kernel(
    const float* __restrict__ part, const int nb, const int half,
    const float* __restrict__ g, const float* __restrict__ bb,
    float* __restrict__ scsh)
{
    __shared__ float ss[256], qq[256];
    const int c = blockIdx.x, t = threadIdx.x;
    float s = 0.f, q = 0.f;
    for (int b = t; b < nb; b += 256) {
        s += part[c * nb + b];
        q += part[(half + c) * nb + b];
    }
    ss[t] = s; qq[t] = q;
    __syncthreads();
    for (int o = 128; o > 0; o >>= 1) {
        if (t < o) { ss[t] += ss[t + o]; qq[t] += qq[t + o]; }
        __syncthreads();
    }
    if (t == 0) {
        const float m = ss[0] * (1.0f / NN);
        const float v = fmaxf(qq[0] * (1.0f / NN) - m * m, 0.0f);
        const float sc = g[c] * rsqrtf(v + 1e-5f);
        scsh[c] = sc;
        scsh[half + c] = bb[c] - m * sc;
    }
}

// ---------------------------------------------------------------------------
// h-prep: h16 = f16(relu(bn2(y2))). One float4 -> half4 per thread.
// Halves gather bytes and removes per-edge-visit BN recompute.
// ---------------------------------------------------------------------------
__global__ __launch_bounds__(256) void hprep_kernel(
    const float* __restrict__ y2, const float* __restrict__ scsh2,
    __half* __restrict__ h16)
{
    const int i4 = (blockIdx.x << 8) + threadIdx.x;   // 3125*256 == NN*64/4
    const float4 v = ((const float4*)y2)[i4];
    const int d0 = (i4 << 2) & 63;
    const float a = fmaxf(fmaf(v.x, scsh2[d0 + 0], scsh2[64 + d0 + 0]), 0.f);
    const float b = fmaxf(fmaf(v.y, scsh2[d0 + 1], scsh2[64 + d0 + 1]), 0.f);
    const float c = fmaxf(fmaf(v.z, scsh2[d0 + 2], scsh2[64 + d0 + 2]), 0.f);
    const float d = fmaxf(fmaf(v.w, scsh2[d0 + 3], scsh2[64 + d0 + 3]), 0.f);
    *(int2*)(h16 + (i4 << 2)) =
        make_int2((int)h2u(__floats2half2_rn(a, b)),
                  (int)h2u(__floats2half2_rn(c, d)));
}

// Layer-0 h-prep: h16 = f16(nemb[x]).
__global__ __launch_bounds__(256) void hprep0_kernel(
    const int* __restrict__ x, const float* __restrict__ nemb,
    __half* __restrict__ h16)
{
    const int i4 = (blockIdx.x << 8) + threadIdx.x;   // 3125*256 == NN*64/4
    const int n = i4 >> 4;
    const float4 v = ((const float4*)nemb)[(x[n] << 4) + (i4 & 15)];
    *(int2*)(h16 + (i4 << 2)) =
        make_int2((int)h2u(__floats2half2_rn(v.x, v.y)),
                  (int)h2u(__floats2half2_rn(v.z, v.w)));
}

// ---------------------------------------------------------------------------
// Gather: one wave per node, 4-edge batched (4 pea + 4 h-gathers in flight).
// acc_d = sum_e relu(h16[src_e][d] + ee_e[d]); z = (1+eps)*h16[n] + acc.
// ---------------------------------------------------------------------------
__global__ __launch_bounds__(256) void gather_kernel(
    const int* __restrict__ off, const int4* __restrict__ pea,
    const __half* __restrict__ h16,
    const float* __restrict__ We, const float* __restrict__ be,
    const float* __restrict__ epsp,
    float* __restrict__ z)
{
    const int t = threadIdx.x;
    const int d = t & 63;
    const int n = (blockIdx.x << 2) + (t >> 6);   // 12500*4 == NN

    const float bed = be[d];
    const float w0 = We[0 * 64 + d], w1 = We[1 * 64 + d], w2 = We[2 * 64 + d],
                w3 = We[3 * 64 + d], w4 = We[4 * 64 + d], w5 = We[5 * 64 + d],
                w6 = We[6 * 64 + d];

    const int e0 = off[n], e1 = off[n + 1];
    float acc = 0.f;
    for (int e = e0; e < e1; e += 4) {
        int idx[4]; float msk[4];
#pragma unroll
        for (int j = 0; j < 4; ++j) {
            const int ej = e + j;
            idx[j] = (ej < e1) ? ej : (e1 - 1);   // clamp: always-valid load
            msk[j] = (ej < e1) ? 1.f : 0.f;
        }
        int4 pk[4];
#pragma unroll
        for (int j = 0; j < 4; ++j) pk[j] = pea[idx[j]];
        float hs[4];
#pragma unroll
        for (int j = 0; j < 4; ++j) {
            const int src = (int)(((unsigned)pk[j].w) >> 16);
            hs[j] = __half2float(h16[(src << 6) + d]);
        }
#pragma unroll
        for (int j = 0; j < 4; ++j) {
            const __half2* hp = reinterpret_cast<const __half2*>(&pk[j]);
            const float2 p01 = __half22float2(hp[0]);
            const float2 p23 = __half22float2(hp[1]);
            const float2 p45 = __half22float2(hp[2]);
            const float p6 = __half2float(
                __ushort_as_half((unsigned short)(pk[j].w & 0xffff)));
            float ee = bed;
            ee = fmaf(p01.x, w0, ee); ee = fmaf(p01.y, w1, ee);
            ee = fmaf(p23.x, w2, ee); ee = fmaf(p23.y, w3, ee);
            ee = fmaf(p45.x, w4, ee); ee = fmaf(p45.y, w5, ee);
            ee = fmaf(p6, w6, ee);
            acc = fmaf(msk[j], fmaxf(hs[j] + ee, 0.f), acc);
        }
    }
    const float hn = __half2float(h16[(n << 6) + d]);
    z[(n << 6) + d] = fmaf(1.0f + epsp[0], hn, acc);
}

// ---------------------------------------------------------------------------
// MM1: y1 = z @ W1 + b1, stored f16. 64x128 tile, K=64 single stage.
// Transposed per-block partials (no atomics). y1h row-aliases z.
// ---------------------------------------------------------------------------
__global__ __launch_bounds__(256) void mm1_kernel(
    const float* __restrict__ z, const float* __restrict__ W1,
    const float* __restrict__ b1p, __half* __restrict__ y1h,
    float* __restrict__ part1)
{
    __shared__ float As[64][68];
    __shared__ float Bs[64][128];
    const int t = threadIdx.x;
    const int r0 = blockIdx.x << 6;
    const int rowg = t & 15, colg = t >> 4;
    const int cbase = colg << 3;

    for (int i = t; i < 1024; i += 256) {       // A: 64 rows x 16 float4
        const int row = i >> 4, c4 = (i & 15) << 2;
        const int r = r0 + row;
        float4 v = make_float4(0.f, 0.f, 0.f, 0.f);
        if (r < NN) v = ((const float4*)z)[(r << 4) + (i & 15)];
        *(float4*)&As[row][c4] = v;
    }
    for (int i = t; i < 2048; i += 256) {       // B: 64x128 = 2048 float4
        ((float4*)&Bs[i >> 5][0])[i & 31] = ((const float4*)W1)[i];
    }
    __syncthreads();

    float acc[4][8];
#pragma unroll
    for (int j = 0; j < 4; ++j)
#pragma unroll
        for (int c = 0; c < 8; ++c) acc[j][c] = 0.f;

#pragma unroll 4
    for (int k = 0; k < 64; ++k) {
        float a[4];
#pragma unroll
        for (int j = 0; j < 4; ++j) a[j] = As[rowg + (j << 4)][k];
        const float4 b0 = *(const float4*)&Bs[k][cbase];
        const float4 b1v = *(const float4*)&Bs[k][cbase + 4];
        const float b[8] = {b0.x, b0.y, b0.z, b0.w, b1v.x, b1v.y, b1v.z, b1v.w};
#pragma unroll
        for (int j = 0; j < 4; ++j)
#pragma unroll
            for (int c = 0; c < 8; ++c)
                acc[j][c] = fmaf(a[j], b[c], acc[j][c]);
    }

    float bv[8];
#pragma unroll
    for (int c = 0; c < 8; ++c) bv[c] = b1p[cbase + c];
    float s[8], sq[8];
#pragma unroll
    for (int c = 0; c < 8; ++c) { s[c] = 0.f; sq[c] = 0.f; }
#pragma unroll
    for (int j = 0; j < 4; ++j) {
        const int r = r0 + rowg + (j << 4);
        if (r < NN) {
            float y[8];
#pragma unroll
            for (int c = 0; c < 8; ++c) y[c] = acc[j][c] + bv[c];
            const unsigned u0 = h2u(__floats2half2_rn(y[0], y[1]));
            const unsigned u1 = h2u(__floats2half2_rn(y[2], y[3]));
            const unsigned u2 = h2u(__floats2half2_rn(y[4], y[5]));
            const unsigned u3 = h2u(__floats2half2_rn(y[6], y[7]));
            *(int4*)(y1h + ((size_t)r << 7) + cbase) =
                make_int4((int)u0, (int)u1, (int)u2, (int)u3);
#pragma unroll
            for (int c = 0; c < 8; ++c) { s[c] += y[c]; sq[c] += y[c] * y[c]; }
        }
    }
#pragma unroll
    for (int c = 0; c < 8; ++c) {
#pragma unroll
        for (int o = 8; o > 0; o >>= 1) {
            s[c] += __shfl_down(s[c], o, 16);
            sq[c] += __shfl_down(sq[c], o, 16);
        }
    }
    if (rowg == 0) {
        const int bid = blockIdx.x;
#pragma unroll
        for (int c = 0; c < 8; ++c) {
            part1[(cbase + c) * NB + bid] = s[c];
            part1[(128 + cbase + c) * NB + bid] = sq[c];
        }
    }
}

// ---------------------------------------------------------------------------
// MM2: y2 = relu(bn1(y1)) @ W2 + b2. 64x64 tile, K=128 single stage.
// ---------------------------------------------------------------------------
__global__ __launch_bounds__(256) void mm2_kernel(
    const __half* __restrict__ y1h, const float* __restrict__ scsh1,
    const float* __restrict__ W2, const float* __restrict__ b2,
    float* __restrict__ y2, float* __restrict__ part2)
{
    __shared__ float As[64][132];
    __shared__ float Bs[128][64];
    __shared__ float sc1[128], sh1[128];
    const int t = threadIdx.x;
    const int r0 = blockIdx.x << 6;
    const int rowg = t & 15, colg = t >> 4;
    const int cbase = colg << 2;

    if (t < 128) { sc1[t] = scsh1[t]; sh1[t] = scsh1[128 + t]; }
    __syncthreads();

    for (int i = t; i < 1024; i += 256) {       // A: 64 rows x 16 half8
        const int row = i >> 4, h8 = i & 15;
        const int r = r0 + row;
        const int k0 = h8 << 3;
        float v[8] = {0.f, 0.f, 0.f, 0.f, 0.f, 0.f, 0.f, 0.f};
        if (r < NN) {
            const int4 pk = *(const int4*)(y1h + ((size_t)r << 7) + k0);
            const __half2* hp = reinterpret_cast<const __half2*>(&pk);
            const float2 f0 = __half22float2(hp[0]);
            const float2 f1 = __half22float2(hp[1]);
            const float2 f2 = __half22float2(hp[2]);
            const float2 f3 = __half22float2(hp[3]);
            const float u[8] = {f0.x, f0.y, f1.x, f1.y, f2.x, f2.y, f3.x, f3.y};
#pragma unroll
            for (int c = 0; c < 8; ++c)
                v[c] = fmaxf(fmaf(u[c], sc1[k0 + c], sh1[k0 + c]), 0.f);
        }
        *(float4*)&As[row][k0] = make_float4(v[0], v[1], v[2], v[3]);
        *(float4*)&As[row][k0 + 4] = make_float4(v[4], v[5], v[6], v[7]);
    }
    for (int i = t; i < 2048; i += 256) {       // B: 128x64 = 2048 float4
        ((float4*)&Bs[i >> 4][0])[i & 15] = ((const float4*)W2)[i];
    }
    __syncthreads();

    float acc[4][4];
#pragma unroll
    for (int j = 0; j < 4; ++j)
#pragma unroll
        for (int c = 0; c < 4; ++c) acc[j][c] = 0.f;

#pragma unroll 4
    for (int k = 0; k < 128; ++k) {
        float a[4];
#pragma unroll
        for (int j = 0; j < 4; ++j) a[j] = As[rowg + (j << 4)][k];
        const float4 b4 = *(const float4*)&Bs[k][cbase];
        const float b[4] = {b4.x, b4.y, b4.z, b4.w};
#pragma unroll
        for (int j = 0; j < 4; ++j)
#pragma unroll
            for (int c = 0; c < 4; ++c)
                acc[j][c] = fmaf(a[j], b[c], acc[j][c]);
    }

    float b2v[4];
#pragma unroll
    for (int c = 0; c < 4; ++c) b2v[c] = b2[cbase + c];
    float s[4], sq[4];
#pragma unroll
    for (int c = 0; c < 4; ++c) { s[c] = 0.f; sq[c] = 0.f; }
#pragma unroll
    for (int j = 0; j < 4; ++j) {
        const int r = r0 + rowg + (j << 4);
        if (r < NN) {
            float y[4];
#pragma unroll
            for (int c = 0; c < 4; ++c) y[c] = acc[j][c] + b2v[c];
            *(float4*)&y2[((size_t)r << 6) + cbase] = make_float4(y[0], y[1], y[2], y[3]);
#pragma unroll
            for (int c = 0; c < 4; ++c) { s[c] += y[c]; sq[c] += y[c] * y[c]; }
        }
    }
#pragma unroll
    for (int c = 0; c < 4; ++c) {
#pragma unroll
        for (int o = 8; o > 0; o >>= 1) {
            s[c] += __shfl_down(s[c], o, 16);
            sq[c] += __shfl_down(sq[c], o, 16);
        }
    }
    if (rowg == 0) {
        const int bid = blockIdx.x;
#pragma unroll
        for (int c = 0; c < 4; ++c) {
            part2[(cbase + c) * NB + bid] = s[c];
            part2[(64 + cbase + c) * NB + bid] = sq[c];
        }
    }
}

// ---------------------------------------------------------------------------
// Final: out = bn2(y2) of layer 4 (no relu on last layer).
// ---------------------------------------------------------------------------
__global__ __launch_bounds__(256) void final_kernel(
    const float* __restrict__ y2, const float* __restrict__ scsh2,
    float* __restrict__ out)
{
    const int i = (blockIdx.x << 8) + threadIdx.x;
    if (i >= NN * 64) return;
    const int d = i & 63;
    out[i] = fmaf(y2[i], scsh2[d], scsh2[64 + d]);
}

extern "C" void kernel_launch(void* const* d_in, const int* in_sizes, int n_in,
                              void* d_out, int out_size, void* d_ws, size_t ws_size,
                              hipStream_t stream)
{
    const int*   x    = (const int*)d_in[0];
    const int*   ei   = (const int*)d_in[1];
    const float* ea   = (const float*)d_in[2];
    const float* nemb = (const float*)d_in[3];
    const float* We   = (const float*)d_in[4];
    const float* be   = (const float*)d_in[5];
    const float* eps  = (const float*)d_in[6];
    const float* W1   = (const float*)d_in[7];
    const float* b1   = (const float*)d_in[8];
    const float* g1   = (const float*)d_in[9];
    const float* bb1  = (const float*)d_in[10];
    const float* W2   = (const float*)d_in[11];
    const float* b2   = (const float*)d_in[12];
    const float* g2   = (const float*)d_in[13];
    const float* bb2  = (const float*)d_in[14];
    float* out = (float*)d_out;

    // workspace layout (4-byte word offsets); total 11,651,072 words = 46.6 MB
    int*   iws   = (int*)d_ws;
    float* fws   = (float*)d_ws;
    int*   off   = iws + 0;          // 50001
    int*   deg   = iws + 50048;      // 50000
    int*   cur   = iws + 100096;     // 50000
    int*   bsum  = iws + 150144;     // 256
    float* scsh1 = fws + 150400;     // 256 (sc128, sh128)
    float* scsh2 = fws + 150656;     // 128 (sc64, sh64)
    float* part1 = fws + 150784;     // 256*782 = 200192
    float* part2 = fws + 350976;     // 128*782 = 100096
    int4*  pea   = (int4*)(iws + 451072);   // 800000 x 16B
    float* z     = fws + 3651072;    // 50000 x 64 f32   } same bytes,
    __half* y1h  = (__half*)(fws + 3651072);// 50000x128  } row-aliased
    float* y2    = fws + 6851072;    // 50000 x 64 f32
    __half* h16  = (__half*)(fws + 10051072); // 50000 x 64 f16 (6.4 MB)

    hipMemsetAsync(deg, 0, 50000 * sizeof(int), stream);

    hist_kernel   <<<3125, 256, 0, stream>>>(ei, deg);
    scanA_kernel  <<<196,  256, 0, stream>>>(deg, bsum);
    scanB_kernel  <<<1,    256, 0, stream>>>(bsum);
    scanC_kernel  <<<196,  256, 0, stream>>>(deg, bsum, off, cur);
    scatter_kernel<<<3125, 256, 0, stream>>>(ei, ea, cur, pea);
    hprep0_kernel <<<3125, 256, 0, stream>>>(x, nemb, h16);

    for (int l = 0; l < 5; ++l) {
        gather_kernel<<<12500, 256, 0, stream>>>(
            off, pea, h16, We + l * 448, be + l * 64, eps + l, z);

        mm1_kernel<<<NB, 256, 0, stream>>>(z, W1 + l * 8192, b1 + l * 128, y1h, part1);

        bnstats_kernel<<<128, 256, 0, stream>>>(part1, NB, 128,
                                                g1 + l * 128, bb1 + l * 128, scsh1);

        mm2_kernel<<<NB, 256, 0, stream>>>(y1h, scsh1, W2 + l * 8192, b2 + l * 64,
                                           y2, part2);

        bnstats_kernel<<<64, 256, 0, stream>>>(part2, NB, 64,
                                               g2 + l * 64, bb2 + l * 64, scsh2);

        if (l < 4)
            hprep_kernel<<<3125, 256, 0, stream>>>(y2, scsh2, h16);
    }

    final_kernel<<<12500, 256, 0, stream>>>(y2, scsh2, out);
}

// Round 6
// 588.161 us; speedup vs baseline: 3.3224x; 1.1351x over previous
//
#include <hip/hip_runtime.h>
#include <hip/hip_fp16.h>

#define NN 50000
#define EE 800000
#define NB 782   // blocks in mm1/mm2 grids

typedef _Float16 f16x8 __attribute__((ext_vector_type(8)));
typedef _Float16 f16x4 __attribute__((ext_vector_type(4)));
typedef float f32x4 __attribute__((ext_vector_type(4)));

// bit-cast helper (no __half2_as_uint in HIP)
__device__ __forceinline__ unsigned h2u(__half2 h) {
    union { __half2 h; unsigned u; } c; c.h = h; return c.u;
}

// ---------------------------------------------------------------------------
// CSR build: hist -> scan (3 phase) -> scatter packed {ea f16 x7, src u16}
// ---------------------------------------------------------------------------
__global__ __launch_bounds__(256) void hist_kernel(const int* __restrict__ ei,
                                                   int* __restrict__ deg) {
    const int e = (blockIdx.x << 8) + threadIdx.x;   // 3125*256 == EE
    atomicAdd(&deg[ei[EE + e]], 1);
}

__global__ __launch_bounds__(256) void scanA_kernel(const int* __restrict__ deg,
                                                    int* __restrict__ bsum) {
    __shared__ int sm[256];
    const int t = threadIdx.x;
    const int i = (blockIdx.x << 8) + t;
    sm[t] = (i < NN) ? deg[i] : 0;
    __syncthreads();
    for (int o = 128; o > 0; o >>= 1) {
        if (t < o) sm[t] += sm[t + o];
        __syncthreads();
    }
    if (t == 0) bsum[blockIdx.x] = sm[0];
}

__global__ __launch_bounds__(256) void scanB_kernel(int* __restrict__ bsum) {
    __shared__ int sm[256];
    const int t = threadIdx.x;
    const int v = (t < 196) ? bsum[t] : 0;
    sm[t] = v;
    __syncthreads();
    for (int o = 1; o < 256; o <<= 1) {
        const int u = (t >= o) ? sm[t - o] : 0;
        __syncthreads();
        sm[t] += u;
        __syncthreads();
    }
    bsum[t] = sm[t] - v;   // exclusive scan of block sums
}

__global__ __launch_bounds__(256) void scanC_kernel(const int* __restrict__ deg,
                                                    const int* __restrict__ bsum,
                                                    int* __restrict__ off,
                                                    int* __restrict__ cur) {
    __shared__ int sm[256];
    const int t = threadIdx.x;
    const int i = (blockIdx.x << 8) + t;
    const int v = (i < NN) ? deg[i] : 0;
    sm[t] = v;
    __syncthreads();
    for (int o = 1; o < 256; o <<= 1) {
        const int u = (t >= o) ? sm[t - o] : 0;
        __syncthreads();
        sm[t] += u;
        __syncthreads();
    }
    const int excl = bsum[blockIdx.x] + sm[t] - v;
    if (i < NN) { off[i] = excl; cur[i] = excl; }
    else if (i == NN) off[NN] = excl;
}

__global__ __launch_bounds__(256) void scatter_kernel(const int* __restrict__ ei,
                                                      const float* __restrict__ ea,
                                                      int* __restrict__ cur,
                                                      int4* __restrict__ pea) {
    const int e = (blockIdx.x << 8) + threadIdx.x;   // 3125*256 == EE
    const int src = ei[e];          // < 50000 < 2^16: packed into w high bits
    const int dst = ei[EE + e];
    const float* a = ea + e * 7;
    const unsigned h0 = __half_as_ushort(__float2half(a[0]));
    const unsigned h1 = __half_as_ushort(__float2half(a[1]));
    const unsigned h2 = __half_as_ushort(__float2half(a[2]));
    const unsigned h3 = __half_as_ushort(__float2half(a[3]));
    const unsigned h4 = __half_as_ushort(__float2half(a[4]));
    const unsigned h5 = __half_as_ushort(__float2half(a[5]));
    const unsigned h6 = __half_as_ushort(__float2half(a[6]));
    const int pos = atomicAdd(&cur[dst], 1);
    pea[pos] = make_int4((int)(h0 | (h1 << 16)), (int)(h2 | (h3 << 16)),
                         (int)(h4 | (h5 << 16)), (int)(h6 | ((unsigned)src << 16)));
}

// ---------------------------------------------------------------------------
// BN stats reduce: one block per column c. part is row-major [nb][2*half]
// (coalesced producer stores, no contended atomics). Emits scale/shift.
// ---------------------------------------------------------------------------
__global__ __launch_bounds__(256) void bnstats_kernel(
    const float* __restrict__ part, const int nb, const int half,
    const float* __restrict__ g, const float* __restrict__ bb,
    float* __restrict__ scsh)
{
    __shared__ float ss[256], qq[256];
    const int c = blockIdx.x, t = threadIdx.x;
    const int stride = half << 1;
    float s = 0.f, q = 0.f;
    for (int b = t; b < nb; b += 256) {
        s += part[b * stride + c];
        q += part[b * stride + half + c];
    }
    ss[t] = s; qq[t] = q;
    __syncthreads();
    for (int o = 128; o > 0; o >>= 1) {
        if (t < o) { ss[t] += ss[t + o]; qq[t] += qq[t + o]; }
        __syncthreads();
    }
    if (t == 0) {
        const float m = ss[0] * (1.0f / NN);
        const float v = fmaxf(qq[0] * (1.0f / NN) - m * m, 0.0f);
        const float sc = g[c] * rsqrtf(v + 1e-5f);
        scsh[c] = sc;
        scsh[half + c] = bb[c] - m * sc;
    }
}

// ---------------------------------------------------------------------------
// W prep: f32 -> f16 weight conversion (W1: 5x8192, W2: 5x8192), once/launch.
// ---------------------------------------------------------------------------
__global__ __launch_bounds__(256) void wprep_kernel(
    const float* __restrict__ W1, const float* __restrict__ W2,
    _Float16* __restrict__ W1h, _Float16* __restrict__ W2h)
{
    const int i = (blockIdx.x << 8) + threadIdx.x;   // 320*256 = 81920
    if (i < 40960) W1h[i] = (_Float16)W1[i];
    else           W2h[i - 40960] = (_Float16)W2[i - 40960];
}

// ---------------------------------------------------------------------------
// h-prep: h16 = f16(relu(bn2(y2))).
// ---------------------------------------------------------------------------
__global__ __launch_bounds__(256) void hprep_kernel(
    const float* __restrict__ y2, const float* __restrict__ scsh2,
    __half* __restrict__ h16)
{
    const int i4 = (blockIdx.x << 8) + threadIdx.x;   // 3125*256 == NN*64/4
    const float4 v = ((const float4*)y2)[i4];
    const int d0 = (i4 << 2) & 63;
    const float a = fmaxf(fmaf(v.x, scsh2[d0 + 0], scsh2[64 + d0 + 0]), 0.f);
    const float b = fmaxf(fmaf(v.y, scsh2[d0 + 1], scsh2[64 + d0 + 1]), 0.f);
    const float c = fmaxf(fmaf(v.z, scsh2[d0 + 2], scsh2[64 + d0 + 2]), 0.f);
    const float d = fmaxf(fmaf(v.w, scsh2[d0 + 3], scsh2[64 + d0 + 3]), 0.f);
    *(int2*)(h16 + (i4 << 2)) =
        make_int2((int)h2u(__floats2half2_rn(a, b)),
                  (int)h2u(__floats2half2_rn(c, d)));
}

// Layer-0 h-prep: h16 = f16(nemb[x]).
__global__ __launch_bounds__(256) void hprep0_kernel(
    const int* __restrict__ x, const float* __restrict__ nemb,
    __half* __restrict__ h16)
{
    const int i4 = (blockIdx.x << 8) + threadIdx.x;   // 3125*256 == NN*64/4
    const int n = i4 >> 4;
    const float4 v = ((const float4*)nemb)[(x[n] << 4) + (i4 & 15)];
    *(int2*)(h16 + (i4 << 2)) =
        make_int2((int)h2u(__floats2half2_rn(v.x, v.y)),
                  (int)h2u(__floats2half2_rn(v.z, v.w)));
}

// ---------------------------------------------------------------------------
// Gather: one wave per node, 4-edge batched. Writes z as f16 (MFMA A input).
// ---------------------------------------------------------------------------
__global__ __launch_bounds__(256) void gather_kernel(
    const int* __restrict__ off, const int4* __restrict__ pea,
    const __half* __restrict__ h16,
    const float* __restrict__ We, const float* __restrict__ be,
    const float* __restrict__ epsp,
    _Float16* __restrict__ z16)
{
    const int t = threadIdx.x;
    const int d = t & 63;
    const int n = (blockIdx.x << 2) + (t >> 6);   // 12500*4 == NN

    const float bed = be[d];
    const float w0 = We[0 * 64 + d], w1 = We[1 * 64 + d], w2 = We[2 * 64 + d],
                w3 = We[3 * 64 + d], w4 = We[4 * 64 + d], w5 = We[5 * 64 + d],
                w6 = We[6 * 64 + d];

    const int e0 = off[n], e1 = off[n + 1];
    float acc = 0.f;
    for (int e = e0; e < e1; e += 4) {
        int idx[4]; float msk[4];
#pragma unroll
        for (int j = 0; j < 4; ++j) {
            const int ej = e + j;
            idx[j] = (ej < e1) ? ej : (e1 - 1);   // clamp: always-valid load
            msk[j] = (ej < e1) ? 1.f : 0.f;
        }
        int4 pk[4];
#pragma unroll
        for (int j = 0; j < 4; ++j) pk[j] = pea[idx[j]];
        float hs[4];
#pragma unroll
        for (int j = 0; j < 4; ++j) {
            const int src = (int)(((unsigned)pk[j].w) >> 16);
            hs[j] = __half2float(h16[(src << 6) + d]);
        }
#pragma unroll
        for (int j = 0; j < 4; ++j) {
            const __half2* hp = reinterpret_cast<const __half2*>(&pk[j]);
            const float2 p01 = __half22float2(hp[0]);
            const float2 p23 = __half22float2(hp[1]);
            const float2 p45 = __half22float2(hp[2]);
            const float p6 = __half2float(
                __ushort_as_half((unsigned short)(pk[j].w & 0xffff)));
            float ee = bed;
            ee = fmaf(p01.x, w0, ee); ee = fmaf(p01.y, w1, ee);
            ee = fmaf(p23.x, w2, ee); ee = fmaf(p23.y, w3, ee);
            ee = fmaf(p45.x, w4, ee); ee = fmaf(p45.y, w5, ee);
            ee = fmaf(p6, w6, ee);
            acc = fmaf(msk[j], fmaxf(hs[j] + ee, 0.f), acc);
        }
    }
    const float hn = __half2float(h16[(n << 6) + d]);
    z16[(n << 6) + d] = (_Float16)fmaf(1.0f + epsp[0], hn, acc);
}

// ---------------------------------------------------------------------------
// MM1 (MFMA f16): y1 = z16 @ W1h + b1, stored f16. Block = 64 rows, 4 waves;
// wave = 16 rows x 128 cols (8 col-tiles x 2 k-steps of 16x16x32 MFMA).
// B staged to LDS fragment-swizzled [k/8][n][k%8] -> one ds_read_b128/frag.
// A-frags direct from global (L2-resident). Stats in-register via shfl_xor
// (C/D layout: col=lane&15, row=(lane>>4)*4+reg), partials row-major.
// z16/y1h padded to 50048 rows; garbage rows are finite (0xAA poison) and
// masked out of stats; they never reach output.
// ---------------------------------------------------------------------------
__global__ __launch_bounds__(256) void mm1_kernel(
    const _Float16* __restrict__ z16, const _Float16* __restrict__ W1h,
    const float* __restrict__ b1p, _Float16* __restrict__ y1h,
    float* __restrict__ part1)
{
    __shared__ _Float16 Bsw[8][128][8];     // [k>>3][n][k&7], 16 KB
    __shared__ float smS[4][128], smQ[4][128];
    const int t = threadIdx.x;
    const int wv = t >> 6, lane = t & 63;
    const int q = lane >> 4, ln = lane & 15;
    const int r0 = blockIdx.x << 6;

    // stage B: W1h[64][128] -> swizzled (4 f16 per thread per pass)
#pragma unroll
    for (int p = 0; p < 8; ++p) {
        const int i4 = t + (p << 8);              // 0..2047
        const int k = i4 >> 5;                    // elem>>7
        const int n = (i4 << 2) & 127;
        const f16x4 w = *(const f16x4*)(W1h + (i4 << 2));
        _Float16* dst = &Bsw[k >> 3][n][k & 7];
        dst[0] = w[0]; dst[8] = w[1]; dst[16] = w[2]; dst[24] = w[3];
    }
    // A-frags: lane holds A[m=ln][k=q*8+j] for k-windows 0 and 32
    const int rowm = r0 + (wv << 4) + ln;
    const f16x8 af0 = *(const f16x8*)(z16 + rowm * 64 + (q << 3));
    const f16x8 af1 = *(const f16x8*)(z16 + rowm * 64 + 32 + (q << 3));
    __syncthreads();

    f32x4 acc[8];
#pragma unroll
    for (int n0 = 0; n0 < 8; ++n0) acc[n0] = (f32x4){0.f, 0.f, 0.f, 0.f};
#pragma unroll
    for (int n0 = 0; n0 < 8; ++n0) {
        const f16x8 bf0 = *(const f16x8*)&Bsw[q][(n0 << 4) + ln][0];
        const f16x8 bf1 = *(const f16x8*)&Bsw[4 + q][(n0 << 4) + ln][0];
        acc[n0] = __builtin_amdgcn_mfma_f32_16x16x32_f16(af0, bf0, acc[n0], 0, 0, 0);
        acc[n0] = __builtin_amdgcn_mfma_f32_16x16x32_f16(af1, bf1, acc[n0], 0, 0, 0);
    }

    // epilogue: bias, f16 store, in-register stats
    const int baseRow = r0 + (wv << 4) + (q << 2);
#pragma unroll
    for (int n0 = 0; n0 < 8; ++n0) {
        const int col = (n0 << 4) + ln;
        const float bb = b1p[col];
        float s = 0.f, sq = 0.f;
#pragma unroll
        for (int rg = 0; rg < 4; ++rg) {
            const int row = baseRow + rg;
            const float y = acc[n0][rg] + bb;
            y1h[row * 128 + col] = (_Float16)y;
            const float m = (row < NN) ? 1.f : 0.f;
            s = fmaf(m, y, s); sq = fmaf(m, y * y, sq);
        }
        s += __shfl_xor(s, 16); s += __shfl_xor(s, 32);
        sq += __shfl_xor(sq, 16); sq += __shfl_xor(sq, 32);
        if (lane < 16) { smS[wv][col] = s; smQ[wv][col] = sq; }
    }
    __syncthreads();
    if (t < 128) {
        const float s = smS[0][t] + smS[1][t] + smS[2][t] + smS[3][t];
        const float q2 = smQ[0][t] + smQ[1][t] + smQ[2][t] + smQ[3][t];
        part1[(blockIdx.x << 8) + t] = s;
        part1[(blockIdx.x << 8) + 128 + t] = q2;
    }
}

// ---------------------------------------------------------------------------
// MM2 (MFMA f16): y2 = relu(bn1(y1h)) @ W2h + b2 (f32 out). Block = 64 rows;
// wave = 16 rows x 64 cols (4 col-tiles x 4 k-steps). BN+relu applied on the
// A-fragment in registers. y2 row-aliases y1h (A reads complete pre-epilogue).
// ---------------------------------------------------------------------------
__global__ __launch_bounds__(256) void mm2_kernel(
    const _Float16* __restrict__ y1h, const float* __restrict__ scsh1,
    const _Float16* __restrict__ W2h, const float* __restrict__ b2,
    float* __restrict__ y2, float* __restrict__ part2)
{
    __shared__ _Float16 Bsw[16][64][8];     // [k>>3][n][k&7], 16 KB
    __shared__ float sc1[128], sh1[128];
    __shared__ float smS[4][64], smQ[4][64];
    const int t = threadIdx.x;
    const int wv = t >> 6, lane = t & 63;
    const int q = lane >> 4, ln = lane & 15;
    const int r0 = blockIdx.x << 6;

    if (t < 128) { sc1[t] = scsh1[t]; sh1[t] = scsh1[128 + t]; }
    // stage B: W2h[128][64] -> swizzled
#pragma unroll
    for (int p = 0; p < 8; ++p) {
        const int i4 = t + (p << 8);              // 0..2047
        const int k = i4 >> 4;                    // elem>>6
        const int n = (i4 << 2) & 63;
        const f16x4 w = *(const f16x4*)(W2h + (i4 << 2));
        _Float16* dst = &Bsw[k >> 3][n][k & 7];
        dst[0] = w[0]; dst[8] = w[1]; dst[16] = w[2]; dst[24] = w[3];
    }
    __syncthreads();

    // A-frags with BN+relu: A[m=ln][k=ks*32+q*8+j]
    const int rowm = r0 + (wv << 4) + ln;
    f16x8 af[4];
#pragma unroll
    for (int ks = 0; ks < 4; ++ks) {
        const f16x8 raw = *(const f16x8*)(y1h + rowm * 128 + (ks << 5) + (q << 3));
        const int k0 = (ks << 5) + (q << 3);
        f16x8 a;
#pragma unroll
        for (int j = 0; j < 8; ++j) {
            const float v = fmaxf(fmaf((float)raw[j], sc1[k0 + j], sh1[k0 + j]), 0.f);
            a[j] = (_Float16)v;
        }
        af[ks] = a;
    }

    f32x4 acc[4];
#pragma unroll
    for (int n0 = 0; n0 < 4; ++n0) acc[n0] = (f32x4){0.f, 0.f, 0.f, 0.f};
#pragma unroll
    for (int n0 = 0; n0 < 4; ++n0) {
#pragma unroll
        for (int ks = 0; ks < 4; ++ks) {
            const f16x8 bf = *(const f16x8*)&Bsw[(ks << 2) + q][(n0 << 4) + ln][0];
            acc[n0] = __builtin_amdgcn_mfma_f32_16x16x32_f16(af[ks], bf, acc[n0], 0, 0, 0);
        }
    }

    // epilogue: bias, f32 store, in-register stats
    const int baseRow = r0 + (wv << 4) + (q << 2);
#pragma unroll
    for (int n0 = 0; n0 < 4; ++n0) {
        const int col = (n0 << 4) + ln;
        const float bb = b2[col];
        float s = 0.f, sq = 0.f;
#pragma unroll
        for (int rg = 0; rg < 4; ++rg) {
            const int row = baseRow + rg;
            const float y = acc[n0][rg] + bb;
            y2[row * 64 + col] = y;
            const float m = (row < NN) ? 1.f : 0.f;
            s = fmaf(m, y, s); sq = fmaf(m, y * y, sq);
        }
        s += __shfl_xor(s, 16); s += __shfl_xor(s, 32);
        sq += __shfl_xor(sq, 16); sq += __shfl_xor(sq, 32);
        if (lane < 16) { smS[wv][col] = s; smQ[wv][col] = sq; }
    }
    __syncthreads();
    if (t < 64) {
        const float s = smS[0][t] + smS[1][t] + smS[2][t] + smS[3][t];
        const float q2 = smQ[0][t] + smQ[1][t] + smQ[2][t] + smQ[3][t];
        part2[(blockIdx.x << 7) + t] = s;
        part2[(blockIdx.x << 7) + 64 + t] = q2;
    }
}

// ---------------------------------------------------------------------------
// Final: out = bn2(y2) of layer 4 (no relu on last layer).
// ---------------------------------------------------------------------------
__global__ __launch_bounds__(256) void final_kernel(
    const float* __restrict__ y2, const float* __restrict__ scsh2,
    float* __restrict__ out)
{
    const int i = (blockIdx.x << 8) + threadIdx.x;
    if (i >= NN * 64) return;
    const int d = i & 63;
    out[i] = fmaf(y2[i], scsh2[d], scsh2[64 + d]);
}

extern "C" void kernel_launch(void* const* d_in, const int* in_sizes, int n_in,
                              void* d_out, int out_size, void* d_ws, size_t ws_size,
                              hipStream_t stream)
{
    const int*   x    = (const int*)d_in[0];
    const int*   ei   = (const int*)d_in[1];
    const float* ea   = (const float*)d_in[2];
    const float* nemb = (const float*)d_in[3];
    const float* We   = (const float*)d_in[4];
    const float* be   = (const float*)d_in[5];
    const float* eps  = (const float*)d_in[6];
    const float* W1   = (const float*)d_in[7];
    const float* b1   = (const float*)d_in[8];
    const float* g1   = (const float*)d_in[9];
    const float* bb1  = (const float*)d_in[10];
    const float* W2   = (const float*)d_in[11];
    const float* b2   = (const float*)d_in[12];
    const float* g2   = (const float*)d_in[13];
    const float* bb2  = (const float*)d_in[14];
    float* out = (float*)d_out;

    // workspace layout (4-byte word offsets); total 10,096,640 words = 40.4 MB
    int*      iws   = (int*)d_ws;
    float*    fws   = (float*)d_ws;
    int*      off   = iws + 0;          // 50001
    int*      deg   = iws + 50048;      // 50000
    int*      cur   = iws + 100096;     // 50000
    int*      bsum  = iws + 150144;     // 256
    float*    scsh1 = fws + 150400;     // 256 (sc128, sh128)
    float*    scsh2 = fws + 150656;     // 128 (sc64, sh64)
    float*    part1 = fws + 150784;     // 782*256 = 200192 (row-major [bid][256])
    float*    part2 = fws + 350976;     // 782*128 = 100096 (row-major [bid][128])
    _Float16* W1h   = (_Float16*)(fws + 451072);  // 5*8192 f16 = 20480 words
    _Float16* W2h   = (_Float16*)(fws + 471552);  // 20480 words
    int4*     pea   = (int4*)(iws + 492032);      // 800000 x 16B
    _Float16* z16   = (_Float16*)(fws + 3692032); // 50048 x 64 f16 (padded rows)
    _Float16* y1h   = (_Float16*)(fws + 5293568); // 50048 x 128 f16 } row-aliased
    float*    y2    = fws + 5293568;              // 50048 x 64 f32  } (256B/row)
    __half*   h16   = (__half*)(fws + 8496640);   // 50000 x 64 f16

    hipMemsetAsync(deg, 0, 50000 * sizeof(int), stream);

    hist_kernel   <<<3125, 256, 0, stream>>>(ei, deg);
    scanA_kernel  <<<196,  256, 0, stream>>>(deg, bsum);
    scanB_kernel  <<<1,    256, 0, stream>>>(bsum);
    scanC_kernel  <<<196,  256, 0, stream>>>(deg, bsum, off, cur);
    scatter_kernel<<<3125, 256, 0, stream>>>(ei, ea, cur, pea);
    wprep_kernel  <<<320,  256, 0, stream>>>(W1, W2, W1h, W2h);
    hprep0_kernel <<<3125, 256, 0, stream>>>(x, nemb, h16);

    for (int l = 0; l < 5; ++l) {
        gather_kernel<<<12500, 256, 0, stream>>>(
            off, pea, h16, We + l * 448, be + l * 64, eps + l, z16);

        mm1_kernel<<<NB, 256, 0, stream>>>(z16, W1h + l * 8192, b1 + l * 128,
                                           y1h, part1);

        bnstats_kernel<<<128, 256, 0, stream>>>(part1, NB, 128,
                                                g1 + l * 128, bb1 + l * 128, scsh1);

        mm2_kernel<<<NB, 256, 0, stream>>>(y1h, scsh1, W2h + l * 8192, b2 + l * 64,
                                           y2, part2);

        bnstats_kernel<<<64, 256, 0, stream>>>(part2, NB, 64,
                                               g2 + l * 64, bb2 + l * 64, scsh2);

        if (l < 4)
            hprep_kernel<<<3125, 256, 0, stream>>>(y2, scsh2, h16);
    }

    final_kernel<<<12500, 256, 0, stream>>>(y2, scsh2, out);
}

// Round 7
// 557.270 us; speedup vs baseline: 3.5066x; 1.0554x over previous
//
#include <hip/hip_runtime.h>
#include <hip/hip_fp16.h>

#define NN 50000
#define EE 800000
#define NB 782   // blocks in mm1/mm2 grids

typedef _Float16 f16x8 __attribute__((ext_vector_type(8)));
typedef _Float16 f16x4 __attribute__((ext_vector_type(4)));
typedef _Float16 f16x2 __attribute__((ext_vector_type(2)));
typedef float f32x4 __attribute__((ext_vector_type(4)));

// bit-cast helpers
__device__ __forceinline__ unsigned h2u(__half2 h) {
    union { __half2 h; unsigned u; } c; c.h = h; return c.u;
}
__device__ __forceinline__ f16x2 u2h(unsigned u) {
    union { unsigned u; f16x2 h; } c; c.u = u; return c.h;
}

// ---------------------------------------------------------------------------
// CSR build: hist -> scan (3 phase) -> scatter packed {ea f16 x7, src u16}
// ---------------------------------------------------------------------------
__global__ __launch_bounds__(256) void hist_kernel(const int* __restrict__ ei,
                                                   int* __restrict__ deg) {
    const int e = (blockIdx.x << 8) + threadIdx.x;   // 3125*256 == EE
    atomicAdd(&deg[ei[EE + e]], 1);
}

__global__ __launch_bounds__(256) void scanA_kernel(const int* __restrict__ deg,
                                                    int* __restrict__ bsum) {
    __shared__ int sm[256];
    const int t = threadIdx.x;
    const int i = (blockIdx.x << 8) + t;
    sm[t] = (i < NN) ? deg[i] : 0;
    __syncthreads();
    for (int o = 128; o > 0; o >>= 1) {
        if (t < o) sm[t] += sm[t + o];
        __syncthreads();
    }
    if (t == 0) bsum[blockIdx.x] = sm[0];
}

__global__ __launch_bounds__(256) void scanB_kernel(int* __restrict__ bsum) {
    __shared__ int sm[256];
    const int t = threadIdx.x;
    const int v = (t < 196) ? bsum[t] : 0;
    sm[t] = v;
    __syncthreads();
    for (int o = 1; o < 256; o <<= 1) {
        const int u = (t >= o) ? sm[t - o] : 0;
        __syncthreads();
        sm[t] += u;
        __syncthreads();
    }
    bsum[t] = sm[t] - v;   // exclusive scan of block sums
}

__global__ __launch_bounds__(256) void scanC_kernel(const int* __restrict__ deg,
                                                    const int* __restrict__ bsum,
                                                    int* __restrict__ off,
                                                    int* __restrict__ cur) {
    __shared__ int sm[256];
    const int t = threadIdx.x;
    const int i = (blockIdx.x << 8) + t;
    const int v = (i < NN) ? deg[i] : 0;
    sm[t] = v;
    __syncthreads();
    for (int o = 1; o < 256; o <<= 1) {
        const int u = (t >= o) ? sm[t - o] : 0;
        __syncthreads();
        sm[t] += u;
        __syncthreads();
    }
    const int excl = bsum[blockIdx.x] + sm[t] - v;
    if (i < NN) { off[i] = excl; cur[i] = excl; }
    else if (i == NN) off[NN] = excl;
}

__global__ __launch_bounds__(256) void scatter_kernel(const int* __restrict__ ei,
                                                      const float* __restrict__ ea,
                                                      int* __restrict__ cur,
                                                      int4* __restrict__ pea) {
    const int e = (blockIdx.x << 8) + threadIdx.x;   // 3125*256 == EE
    const int src = ei[e];          // < 50000 < 2^16: packed into w high bits
    const int dst = ei[EE + e];
    const float* a = ea + e * 7;
    const unsigned h0 = __half_as_ushort(__float2half(a[0]));
    const unsigned h1 = __half_as_ushort(__float2half(a[1]));
    const unsigned h2 = __half_as_ushort(__float2half(a[2]));
    const unsigned h3 = __half_as_ushort(__float2half(a[3]));
    const unsigned h4 = __half_as_ushort(__float2half(a[4]));
    const unsigned h5 = __half_as_ushort(__float2half(a[5]));
    const unsigned h6 = __half_as_ushort(__float2half(a[6]));
    const int pos = atomicAdd(&cur[dst], 1);
    pea[pos] = make_int4((int)(h0 | (h1 << 16)), (int)(h2 | (h3 << 16)),
                         (int)(h4 | (h5 << 16)), (int)(h6 | ((unsigned)src << 16)));
}

// ---------------------------------------------------------------------------
// BN stats reduce: one block per column c. part is row-major [nb][2*half].
// ---------------------------------------------------------------------------
__global__ __launch_bounds__(256) void bnstats_kernel(
    const float* __restrict__ part, const int nb, const int half,
    const float* __restrict__ g, const float* __restrict__ bb,
    float* __restrict__ scsh)
{
    __shared__ float ss[256], qq[256];
    const int c = blockIdx.x, t = threadIdx.x;
    const int stride = half << 1;
    float s = 0.f, q = 0.f;
    for (int b = t; b < nb; b += 256) {
        s += part[b * stride + c];
        q += part[b * stride + half + c];
    }
    ss[t] = s; qq[t] = q;
    __syncthreads();
    for (int o = 128; o > 0; o >>= 1) {
        if (t < o) { ss[t] += ss[t + o]; qq[t] += qq[t + o]; }
        __syncthreads();
    }
    if (t == 0) {
        const float m = ss[0] * (1.0f / NN);
        const float v = fmaxf(qq[0] * (1.0f / NN) - m * m, 0.0f);
        const float sc = g[c] * rsqrtf(v + 1e-5f);
        scsh[c] = sc;
        scsh[half + c] = bb[c] - m * sc;
    }
}

// ---------------------------------------------------------------------------
// W prep (once/launch): W1/W2 -> f16 pre-swizzled into MFMA B-fragment
// layout [k>>3][n][k&7] (so a B-frag is one coalesced 16B global load),
// We -> per-lane packed half2 pairs Wep[l][d] = {(w0,w1),(w2,w3),(w4,w5),(w6,0)}.
// ---------------------------------------------------------------------------
__global__ __launch_bounds__(256) void wprep_kernel(
    const float* __restrict__ W1, const float* __restrict__ W2,
    const float* __restrict__ We,
    _Float16* __restrict__ W1s, _Float16* __restrict__ W2s,
    uint4* __restrict__ Wep)
{
    const int i = (blockIdx.x << 8) + threadIdx.x;   // 322 blocks
    if (i < 40960) {
        const int l = i >> 13, j = i & 8191, k = j >> 7, n = j & 127;
        W1s[(l << 13) + ((((k >> 3) << 7) + n) << 3) + (k & 7)] = (_Float16)W1[i];
    } else if (i < 81920) {
        const int i2 = i - 40960;
        const int l = i2 >> 13, j = i2 & 8191, k = j >> 6, n = j & 63;
        W2s[(l << 13) + ((((k >> 3) << 6) + n) << 3) + (k & 7)] = (_Float16)W2[i2];
    } else if (i < 82240) {
        const int i3 = i - 81920;            // 0..319
        const int l = i3 >> 6, d = i3 & 63;
        const float* W = We + l * 448;
        const unsigned p0 = __half_as_ushort(__float2half(W[0 * 64 + d]));
        const unsigned p1 = __half_as_ushort(__float2half(W[1 * 64 + d]));
        const unsigned p2 = __half_as_ushort(__float2half(W[2 * 64 + d]));
        const unsigned p3 = __half_as_ushort(__float2half(W[3 * 64 + d]));
        const unsigned p4 = __half_as_ushort(__float2half(W[4 * 64 + d]));
        const unsigned p5 = __half_as_ushort(__float2half(W[5 * 64 + d]));
        const unsigned p6 = __half_as_ushort(__float2half(W[6 * 64 + d]));
        Wep[i3] = make_uint4(p0 | (p1 << 16), p2 | (p3 << 16),
                             p4 | (p5 << 16), p6);
    }
}

// ---------------------------------------------------------------------------
// h-prep: h16 = f16(relu(bn2(y2))).
// ---------------------------------------------------------------------------
__global__ __launch_bounds__(256) void hprep_kernel(
    const float* __restrict__ y2, const float* __restrict__ scsh2,
    __half* __restrict__ h16)
{
    const int i4 = (blockIdx.x << 8) + threadIdx.x;   // 3125*256 == NN*64/4
    const float4 v = ((const float4*)y2)[i4];
    const int d0 = (i4 << 2) & 63;
    const float a = fmaxf(fmaf(v.x, scsh2[d0 + 0], scsh2[64 + d0 + 0]), 0.f);
    const float b = fmaxf(fmaf(v.y, scsh2[d0 + 1], scsh2[64 + d0 + 1]), 0.f);
    const float c = fmaxf(fmaf(v.z, scsh2[d0 + 2], scsh2[64 + d0 + 2]), 0.f);
    const float d = fmaxf(fmaf(v.w, scsh2[d0 + 3], scsh2[64 + d0 + 3]), 0.f);
    *(int2*)(h16 + (i4 << 2)) =
        make_int2((int)h2u(__floats2half2_rn(a, b)),
                  (int)h2u(__floats2half2_rn(c, d)));
}

// Layer-0 h-prep: h16 = f16(nemb[x]).
__global__ __launch_bounds__(256) void hprep0_kernel(
    const int* __restrict__ x, const float* __restrict__ nemb,
    __half* __restrict__ h16)
{
    const int i4 = (blockIdx.x << 8) + threadIdx.x;   // 3125*256 == NN*64/4
    const int n = i4 >> 4;
    const float4 v = ((const float4*)nemb)[(x[n] << 4) + (i4 & 15)];
    *(int2*)(h16 + (i4 << 2)) =
        make_int2((int)h2u(__floats2half2_rn(v.x, v.y)),
                  (int)h2u(__floats2half2_rn(v.z, v.w)));
}

// ---------------------------------------------------------------------------
// Gather: one wave per node, 8-edge batched, dot2-based edge encoder
// (3 v_dot2_f32_f16 + 2 fma + 2 cvt per edge vs ~22 scalar ops before).
// ---------------------------------------------------------------------------
__global__ __launch_bounds__(256) void gather_kernel(
    const int* __restrict__ off, const int4* __restrict__ pea,
    const __half* __restrict__ h16,
    const uint4* __restrict__ Wep, const float* __restrict__ be,
    const float* __restrict__ epsp,
    _Float16* __restrict__ z16)
{
    const int t = threadIdx.x;
    const int d = t & 63;
    const int n = (blockIdx.x << 2) + (t >> 6);   // 12500*4 == NN

    const uint4 wp = Wep[d];
    const f16x2 w01 = u2h(wp.x), w23 = u2h(wp.y), w45 = u2h(wp.z);
    const float w6 = __half2float(__ushort_as_half((unsigned short)(wp.w & 0xffff)));
    const float bed = be[d];

    const int e0 = off[n], e1 = off[n + 1];
    float acc = 0.f;
    for (int e = e0; e < e1; e += 8) {
        int4 pk[8]; float msk[8];
#pragma unroll
        for (int j = 0; j < 8; ++j) {
            const int ej = e + j;
            const int id = (ej < e1) ? ej : (e1 - 1);   // clamp: always-valid
            msk[j] = (ej < e1) ? 1.f : 0.f;
            pk[j] = pea[id];
        }
        float hs[8];
#pragma unroll
        for (int j = 0; j < 8; ++j) {
            const int src = (int)(((unsigned)pk[j].w) >> 16);
            hs[j] = __half2float(h16[(src << 6) + d]);
        }
#pragma unroll
        for (int j = 0; j < 8; ++j) {
            const float p6 = __half2float(
                __ushort_as_half((unsigned short)(pk[j].w & 0xffff)));
            float ee = fmaf(p6, w6, bed);
            ee = __builtin_amdgcn_fdot2(u2h((unsigned)pk[j].x), w01, ee, false);
            ee = __builtin_amdgcn_fdot2(u2h((unsigned)pk[j].y), w23, ee, false);
            ee = __builtin_amdgcn_fdot2(u2h((unsigned)pk[j].z), w45, ee, false);
            acc = fmaf(msk[j], fmaxf(hs[j] + ee, 0.f), acc);
        }
    }
    const float hn = __half2float(h16[(n << 6) + d]);
    z16[(n << 6) + d] = (_Float16)fmaf(1.0f + epsp[0], hn, acc);
}

// ---------------------------------------------------------------------------
// MM1 (MFMA f16): y1 = z16 @ W1 + b1, f16 out. Block = 64 rows, 4 waves;
// wave = 16 rows x 128 cols. B-frags read directly from pre-swizzled W1s
// (L2-hot, coalesced) — no LDS staging, no pre-compute barrier.
// Stats in-register (C/D: col=lane&15, row=(lane>>4)*4+reg), row-major parts.
// ---------------------------------------------------------------------------
__global__ __launch_bounds__(256) void mm1_kernel(
    const _Float16* __restrict__ z16, const _Float16* __restrict__ W1s,
    const float* __restrict__ b1p, _Float16* __restrict__ y1h,
    float* __restrict__ part1)
{
    __shared__ float smS[4][128], smQ[4][128];
    const int t = threadIdx.x;
    const int wv = t >> 6, lane = t & 63;
    const int q = lane >> 4, ln = lane & 15;
    const int r0 = blockIdx.x << 6;

    const int rowm = r0 + (wv << 4) + ln;
    const f16x8 af0 = *(const f16x8*)(z16 + rowm * 64 + (q << 3));
    const f16x8 af1 = *(const f16x8*)(z16 + rowm * 64 + 32 + (q << 3));

    f32x4 acc[8];
#pragma unroll
    for (int n0 = 0; n0 < 8; ++n0) acc[n0] = (f32x4){0.f, 0.f, 0.f, 0.f};
#pragma unroll
    for (int n0 = 0; n0 < 8; ++n0) {
        const f16x8 bf0 = *(const f16x8*)(W1s + (((q << 7) + (n0 << 4) + ln) << 3));
        const f16x8 bf1 = *(const f16x8*)(W1s + ((((4 + q) << 7) + (n0 << 4) + ln) << 3));
        acc[n0] = __builtin_amdgcn_mfma_f32_16x16x32_f16(af0, bf0, acc[n0], 0, 0, 0);
        acc[n0] = __builtin_amdgcn_mfma_f32_16x16x32_f16(af1, bf1, acc[n0], 0, 0, 0);
    }

    const int baseRow = r0 + (wv << 4) + (q << 2);
#pragma unroll
    for (int n0 = 0; n0 < 8; ++n0) {
        const int col = (n0 << 4) + ln;
        const float bb = b1p[col];
        float s = 0.f, sq = 0.f;
#pragma unroll
        for (int rg = 0; rg < 4; ++rg) {
            const int row = baseRow + rg;
            const float y = acc[n0][rg] + bb;
            y1h[row * 128 + col] = (_Float16)y;
            const float m = (row < NN) ? 1.f : 0.f;
            s = fmaf(m, y, s); sq = fmaf(m, y * y, sq);
        }
        s += __shfl_xor(s, 16); s += __shfl_xor(s, 32);
        sq += __shfl_xor(sq, 16); sq += __shfl_xor(sq, 32);
        if (lane < 16) { smS[wv][col] = s; smQ[wv][col] = sq; }
    }
    __syncthreads();
    if (t < 128) {
        const float s = smS[0][t] + smS[1][t] + smS[2][t] + smS[3][t];
        const float q2 = smQ[0][t] + smQ[1][t] + smQ[2][t] + smQ[3][t];
        part1[(blockIdx.x << 8) + t] = s;
        part1[(blockIdx.x << 8) + 128 + t] = q2;
    }
}

// ---------------------------------------------------------------------------
// MM2 (MFMA f16): y2 = relu(bn1(y1h)) @ W2 + b2 (f32 out). Block = 64 rows.
// BN scale/shift via tiny L2-hot global loads; B-frags from W2s. No LDS
// staging. y2 row-aliases y1h (A reads complete before epilogue stores).
// ---------------------------------------------------------------------------
__global__ __launch_bounds__(256) void mm2_kernel(
    const _Float16* __restrict__ y1h, const float* __restrict__ scsh1,
    const _Float16* __restrict__ W2s, const float* __restrict__ b2,
    float* __restrict__ y2, float* __restrict__ part2)
{
    __shared__ float smS[4][64], smQ[4][64];
    const int t = threadIdx.x;
    const int wv = t >> 6, lane = t & 63;
    const int q = lane >> 4, ln = lane & 15;
    const int r0 = blockIdx.x << 6;

    const int rowm = r0 + (wv << 4) + ln;
    f16x8 af[4];
#pragma unroll
    for (int ks = 0; ks < 4; ++ks) {
        const int k0 = (ks << 5) + (q << 3);
        const f16x8 raw = *(const f16x8*)(y1h + rowm * 128 + k0);
        const float4 scA = *(const float4*)(scsh1 + k0);
        const float4 scB = *(const float4*)(scsh1 + k0 + 4);
        const float4 shA = *(const float4*)(scsh1 + 128 + k0);
        const float4 shB = *(const float4*)(scsh1 + 128 + k0 + 4);
        const float sc[8] = {scA.x, scA.y, scA.z, scA.w, scB.x, scB.y, scB.z, scB.w};
        const float sh[8] = {shA.x, shA.y, shA.z, shA.w, shB.x, shB.y, shB.z, shB.w};
        f16x8 a;
#pragma unroll
        for (int j = 0; j < 8; ++j)
            a[j] = (_Float16)fmaxf(fmaf((float)raw[j], sc[j], sh[j]), 0.f);
        af[ks] = a;
    }

    f32x4 acc[4];
#pragma unroll
    for (int n0 = 0; n0 < 4; ++n0) acc[n0] = (f32x4){0.f, 0.f, 0.f, 0.f};
#pragma unroll
    for (int n0 = 0; n0 < 4; ++n0) {
#pragma unroll
        for (int ks = 0; ks < 4; ++ks) {
            const f16x8 bf = *(const f16x8*)(
                W2s + (((((ks << 2) + q) << 6) + (n0 << 4) + ln) << 3));
            acc[n0] = __builtin_amdgcn_mfma_f32_16x16x32_f16(af[ks], bf, acc[n0], 0, 0, 0);
        }
    }

    const int baseRow = r0 + (wv << 4) + (q << 2);
#pragma unroll
    for (int n0 = 0; n0 < 4; ++n0) {
        const int col = (n0 << 4) + ln;
        const float bb = b2[col];
        float s = 0.f, sq = 0.f;
#pragma unroll
        for (int rg = 0; rg < 4; ++rg) {
            const int row = baseRow + rg;
            const float y = acc[n0][rg] + bb;
            y2[row * 64 + col] = y;
            const float m = (row < NN) ? 1.f : 0.f;
            s = fmaf(m, y, s); sq = fmaf(m, y * y, sq);
        }
        s += __shfl_xor(s, 16); s += __shfl_xor(s, 32);
        sq += __shfl_xor(sq, 16); sq += __shfl_xor(sq, 32);
        if (lane < 16) { smS[wv][col] = s; smQ[wv][col] = sq; }
    }
    __syncthreads();
    if (t < 64) {
        const float s = smS[0][t] + smS[1][t] + smS[2][t] + smS[3][t];
        const float q2 = smQ[0][t] + smQ[1][t] + smQ[2][t] + smQ[3][t];
        part2[(blockIdx.x << 7) + t] = s;
        part2[(blockIdx.x << 7) + 64 + t] = q2;
    }
}

// ---------------------------------------------------------------------------
// Final: out = bn2(y2) of layer 4 (no relu on last layer).
// ---------------------------------------------------------------------------
__global__ __launch_bounds__(256) void final_kernel(
    const float* __restrict__ y2, const float* __restrict__ scsh2,
    float* __restrict__ out)
{
    const int i = (blockIdx.x << 8) + threadIdx.x;
    if (i >= NN * 64) return;
    const int d = i & 63;
    out[i] = fmaf(y2[i], scsh2[d], scsh2[64 + d]);
}

extern "C" void kernel_launch(void* const* d_in, const int* in_sizes, int n_in,
                              void* d_out, int out_size, void* d_ws, size_t ws_size,
                              hipStream_t stream)
{
    const int*   x    = (const int*)d_in[0];
    const int*   ei   = (const int*)d_in[1];
    const float* ea   = (const float*)d_in[2];
    const float* nemb = (const float*)d_in[3];
    const float* We   = (const float*)d_in[4];
    const float* be   = (const float*)d_in[5];
    const float* eps  = (const float*)d_in[6];
    const float* W1   = (const float*)d_in[7];
    const float* b1   = (const float*)d_in[8];
    const float* g1   = (const float*)d_in[9];
    const float* bb1  = (const float*)d_in[10];
    const float* W2   = (const float*)d_in[11];
    const float* b2   = (const float*)d_in[12];
    const float* g2   = (const float*)d_in[13];
    const float* bb2  = (const float*)d_in[14];
    float* out = (float*)d_out;

    // workspace layout (4-byte word offsets); total 10,097,920 words = 40.4 MB
    int*      iws   = (int*)d_ws;
    float*    fws   = (float*)d_ws;
    int*      off   = iws + 0;          // 50001
    int*      deg   = iws + 50048;      // 50000
    int*      cur   = iws + 100096;     // 50000
    int*      bsum  = iws + 150144;     // 256
    float*    scsh1 = fws + 150400;     // 256 (sc128, sh128)
    float*    scsh2 = fws + 150656;     // 128 (sc64, sh64)
    float*    part1 = fws + 150784;     // 782*256 (row-major [bid][256])
    float*    part2 = fws + 350976;     // 782*128 (row-major [bid][128])
    _Float16* W1s   = (_Float16*)(fws + 451072);  // 5*8192 f16 swizzled
    _Float16* W2s   = (_Float16*)(fws + 471552);  // 5*8192 f16 swizzled
    uint4*    Wep   = (uint4*)(fws + 492032);     // 5*64 uint4 (1280 words)
    int4*     pea   = (int4*)(iws + 493312);      // 800000 x 16B
    _Float16* z16   = (_Float16*)(fws + 3693312); // 50048 x 64 f16 (padded)
    _Float16* y1h   = (_Float16*)(fws + 5294848); // 50048 x 128 f16 } row-
    float*    y2    = fws + 5294848;              // 50048 x 64 f32  } aliased
    __half*   h16   = (__half*)(fws + 8497920);   // 50000 x 64 f16

    hipMemsetAsync(deg, 0, 50000 * sizeof(int), stream);

    hist_kernel   <<<3125, 256, 0, stream>>>(ei, deg);
    scanA_kernel  <<<196,  256, 0, stream>>>(deg, bsum);
    scanB_kernel  <<<1,    256, 0, stream>>>(bsum);
    scanC_kernel  <<<196,  256, 0, stream>>>(deg, bsum, off, cur);
    scatter_kernel<<<3125, 256, 0, stream>>>(ei, ea, cur, pea);
    wprep_kernel  <<<322,  256, 0, stream>>>(W1, W2, We, W1s, W2s, Wep);
    hprep0_kernel <<<3125, 256, 0, stream>>>(x, nemb, h16);

    for (int l = 0; l < 5; ++l) {
        gather_kernel<<<12500, 256, 0, stream>>>(
            off, pea, h16, Wep + l * 64, be + l * 64, eps + l, z16);

        mm1_kernel<<<NB, 256, 0, stream>>>(z16, W1s + l * 8192, b1 + l * 128,
                                           y1h, part1);

        bnstats_kernel<<<128, 256, 0, stream>>>(part1, NB, 128,
                                                g1 + l * 128, bb1 + l * 128, scsh1);

        mm2_kernel<<<NB, 256, 0, stream>>>(y1h, scsh1, W2s + l * 8192, b2 + l * 64,
                                           y2, part2);

        bnstats_kernel<<<64, 256, 0, stream>>>(part2, NB, 64,
                                               g2 + l * 64, bb2 + l * 64, scsh2);

        if (l < 4)
            hprep_kernel<<<3125, 256, 0, stream>>>(y2, scsh2, h16);
    }

    final_kernel<<<12500, 256, 0, stream>>>(y2, scsh2, out);
}

// Round 8
// 490.508 us; speedup vs baseline: 3.9838x; 1.1361x over previous
//
#include <hip/hip_runtime.h>
#include <hip/hip_fp16.h>

#define NN 50000
#define EE 800000
#define NB 782   // blocks in mm1/mm2 grids

typedef _Float16 f16x8 __attribute__((ext_vector_type(8)));
typedef _Float16 f16x4 __attribute__((ext_vector_type(4)));
typedef _Float16 f16x2 __attribute__((ext_vector_type(2)));
typedef float f32x4 __attribute__((ext_vector_type(4)));

// bit-cast helpers
__device__ __forceinline__ unsigned h2u(__half2 h) {
    union { __half2 h; unsigned u; } c; c.h = h; return c.u;
}
__device__ __forceinline__ f16x2 u2h(unsigned u) {
    union { unsigned u; f16x2 h; } c; c.u = u; return c.h;
}

// ---------------------------------------------------------------------------
// CSR build: hist -> scan (3 phase) -> scatter packed {ea f16 x7, src u16}
// ---------------------------------------------------------------------------
__global__ __launch_bounds__(256) void hist_kernel(const int* __restrict__ ei,
                                                   int* __restrict__ deg) {
    const int e = (blockIdx.x << 8) + threadIdx.x;   // 3125*256 == EE
    atomicAdd(&deg[ei[EE + e]], 1);
}

__global__ __launch_bounds__(256) void scanA_kernel(const int* __restrict__ deg,
                                                    int* __restrict__ bsum) {
    __shared__ int sm[256];
    const int t = threadIdx.x;
    const int i = (blockIdx.x << 8) + t;
    sm[t] = (i < NN) ? deg[i] : 0;
    __syncthreads();
    for (int o = 128; o > 0; o >>= 1) {
        if (t < o) sm[t] += sm[t + o];
        __syncthreads();
    }
    if (t == 0) bsum[blockIdx.x] = sm[0];
}

__global__ __launch_bounds__(256) void scanB_kernel(int* __restrict__ bsum) {
    __shared__ int sm[256];
    const int t = threadIdx.x;
    const int v = (t < 196) ? bsum[t] : 0;
    sm[t] = v;
    __syncthreads();
    for (int o = 1; o < 256; o <<= 1) {
        const int u = (t >= o) ? sm[t - o] : 0;
        __syncthreads();
        sm[t] += u;
        __syncthreads();
    }
    bsum[t] = sm[t] - v;   // exclusive scan of block sums
}

__global__ __launch_bounds__(256) void scanC_kernel(const int* __restrict__ deg,
                                                    const int* __restrict__ bsum,
                                                    int* __restrict__ off,
                                                    int* __restrict__ cur) {
    __shared__ int sm[256];
    const int t = threadIdx.x;
    const int i = (blockIdx.x << 8) + t;
    const int v = (i < NN) ? deg[i] : 0;
    sm[t] = v;
    __syncthreads();
    for (int o = 1; o < 256; o <<= 1) {
        const int u = (t >= o) ? sm[t - o] : 0;
        __syncthreads();
        sm[t] += u;
        __syncthreads();
    }
    const int excl = bsum[blockIdx.x] + sm[t] - v;
    if (i < NN) { off[i] = excl; cur[i] = excl; }
    else if (i == NN) off[NN] = excl;
}

__global__ __launch_bounds__(256) void scatter_kernel(const int* __restrict__ ei,
                                                      const float* __restrict__ ea,
                                                      int* __restrict__ cur,
                                                      int4* __restrict__ pea) {
    const int e = (blockIdx.x << 8) + threadIdx.x;   // 3125*256 == EE
    const int src = ei[e];          // < 50000 < 2^16: packed into w high bits
    const int dst = ei[EE + e];
    const float* a = ea + e * 7;
    const unsigned h0 = __half_as_ushort(__float2half(a[0]));
    const unsigned h1 = __half_as_ushort(__float2half(a[1]));
    const unsigned h2 = __half_as_ushort(__float2half(a[2]));
    const unsigned h3 = __half_as_ushort(__float2half(a[3]));
    const unsigned h4 = __half_as_ushort(__float2half(a[4]));
    const unsigned h5 = __half_as_ushort(__float2half(a[5]));
    const unsigned h6 = __half_as_ushort(__float2half(a[6]));
    const int pos = atomicAdd(&cur[dst], 1);
    pea[pos] = make_int4((int)(h0 | (h1 << 16)), (int)(h2 | (h3 << 16)),
                         (int)(h4 | (h5 << 16)), (int)(h6 | ((unsigned)src << 16)));
}

// ---------------------------------------------------------------------------
// BN stats reduce: one block per column c. part is row-major [nb][2*half].
// ---------------------------------------------------------------------------
__global__ __launch_bounds__(256) void bnstats_kernel(
    const float* __restrict__ part, const int nb, const int half,
    const float* __restrict__ g, const float* __restrict__ bb,
    float* __restrict__ scsh)
{
    __shared__ float ss[256], qq[256];
    const int c = blockIdx.x, t = threadIdx.x;
    const int stride = half << 1;
    float s = 0.f, q = 0.f;
    for (int b = t; b < nb; b += 256) {
        s += part[b * stride + c];
        q += part[b * stride + half + c];
    }
    ss[t] = s; qq[t] = q;
    __syncthreads();
    for (int o = 128; o > 0; o >>= 1) {
        if (t < o) { ss[t] += ss[t + o]; qq[t] += qq[t + o]; }
        __syncthreads();
    }
    if (t == 0) {
        const float m = ss[0] * (1.0f / NN);
        const float v = fmaxf(qq[0] * (1.0f / NN) - m * m, 0.0f);
        const float sc = g[c] * rsqrtf(v + 1e-5f);
        scsh[c] = sc;
        scsh[half + c] = bb[c] - m * sc;
    }
}

// ---------------------------------------------------------------------------
// W prep (once/launch): W1/W2 -> f16 pre-swizzled MFMA B-frag layout;
// We -> packed half2 per dim-pair Wepk[l][k][s] = {We[k][2s],We[k][2s+1]};
// be -> be2[l][s] = {be[2s], be[2s+1]}.  Total 83200 elems = 325 blocks.
// ---------------------------------------------------------------------------
__global__ __launch_bounds__(256) void wprep_kernel(
    const float* __restrict__ W1, const float* __restrict__ W2,
    const float* __restrict__ We, const float* __restrict__ be,
    _Float16* __restrict__ W1s, _Float16* __restrict__ W2s,
    unsigned* __restrict__ Wepk, unsigned* __restrict__ be2)
{
    const int i = (blockIdx.x << 8) + threadIdx.x;
    if (i < 40960) {
        const int l = i >> 13, j = i & 8191, k = j >> 7, n = j & 127;
        W1s[(l << 13) + ((((k >> 3) << 7) + n) << 3) + (k & 7)] = (_Float16)W1[i];
    } else if (i < 81920) {
        const int i2 = i - 40960;
        const int l = i2 >> 13, j = i2 & 8191, k = j >> 6, n = j & 63;
        W2s[(l << 13) + ((((k >> 3) << 6) + n) << 3) + (k & 7)] = (_Float16)W2[i2];
    } else if (i < 83040) {
        const int i3 = i - 81920;            // 0..1119 = [l][k][s]
        const int l = i3 / 224;
        const int r = i3 - l * 224;
        const int k = r >> 5, s = r & 31;
        const float* W = We + l * 448 + (k << 6) + (s << 1);
        Wepk[i3] = h2u(__floats2half2_rn(W[0], W[1]));
    } else if (i < 83200) {
        const int i4 = i - 83040;            // 0..159 = [l][s]
        const int l = i4 >> 5, s = i4 & 31;
        const float* B = be + (l << 6) + (s << 1);
        be2[i4] = h2u(__floats2half2_rn(B[0], B[1]));
    }
}

// ---------------------------------------------------------------------------
// h-prep: h16 = f16(relu(bn2(y2))).
// ---------------------------------------------------------------------------
__global__ __launch_bounds__(256) void hprep_kernel(
    const float* __restrict__ y2, const float* __restrict__ scsh2,
    __half* __restrict__ h16)
{
    const int i4 = (blockIdx.x << 8) + threadIdx.x;   // 3125*256 == NN*64/4
    const float4 v = ((const float4*)y2)[i4];
    const int d0 = (i4 << 2) & 63;
    const float a = fmaxf(fmaf(v.x, scsh2[d0 + 0], scsh2[64 + d0 + 0]), 0.f);
    const float b = fmaxf(fmaf(v.y, scsh2[d0 + 1], scsh2[64 + d0 + 1]), 0.f);
    const float c = fmaxf(fmaf(v.z, scsh2[d0 + 2], scsh2[64 + d0 + 2]), 0.f);
    const float d = fmaxf(fmaf(v.w, scsh2[d0 + 3], scsh2[64 + d0 + 3]), 0.f);
    *(int2*)(h16 + (i4 << 2)) =
        make_int2((int)h2u(__floats2half2_rn(a, b)),
                  (int)h2u(__floats2half2_rn(c, d)));
}

// Layer-0 h-prep: h16 = f16(nemb[x]).
__global__ __launch_bounds__(256) void hprep0_kernel(
    const int* __restrict__ x, const float* __restrict__ nemb,
    __half* __restrict__ h16)
{
    const int i4 = (blockIdx.x << 8) + threadIdx.x;   // 3125*256 == NN*64/4
    const int n = i4 >> 4;
    const float4 v = ((const float4*)nemb)[(x[n] << 4) + (i4 & 15)];
    *(int2*)(h16 + (i4 << 2)) =
        make_int2((int)h2u(__floats2half2_rn(v.x, v.y)),
                  (int)h2u(__floats2half2_rn(v.z, v.w)));
}

// ---------------------------------------------------------------------------
// Gather (half-wave packed): 2 nodes per wave, lane owns 2 dims as half2.
// Edge encoder = 7 v_pk_fma_f16 (op_sel splats), relu = pk_max, acc in f32.
// Per-edge wave-ops ~9.5 vs 18 in the lane-per-dim version; 2 mem lines/edge.
// ---------------------------------------------------------------------------
__global__ __launch_bounds__(256) void gather_kernel(
    const int* __restrict__ off, const int4* __restrict__ pea,
    const unsigned* __restrict__ h32,      // h16 rows viewed as 32 dwords
    const unsigned* __restrict__ Wepk, const unsigned* __restrict__ be2,
    const float* __restrict__ epsp,
    unsigned* __restrict__ z32)            // z16 rows viewed as 32 dwords
{
    const int t = threadIdx.x;
    const int lane = t & 63;
    const int s = lane & 31;
    const int n = (blockIdx.x << 3) + ((t >> 6) << 1) + (lane >> 5); // 6250*8

    const f16x2 w0 = u2h(Wepk[s]),       w1 = u2h(Wepk[32 + s]),
                w2 = u2h(Wepk[64 + s]),  w3 = u2h(Wepk[96 + s]),
                w4 = u2h(Wepk[128 + s]), w5 = u2h(Wepk[160 + s]),
                w6 = u2h(Wepk[192 + s]);
    const f16x2 beh = u2h(be2[s]);

    const int e0 = off[n], e1 = off[n + 1];
    const int deg = e1 - e0;
    const int degMax = max(deg, __shfl_xor(deg, 32));

    float aLo = 0.f, aHi = 0.f;
    for (int i = 0; i < degMax; i += 8) {
        int4 pk[8]; int vld[8];
#pragma unroll
        for (int j = 0; j < 8; ++j) {
            const int ej = e0 + i + j;
            vld[j] = (ej < e1);
            pk[j] = pea[vld[j] ? ej : 0];   // clamp to 0: always in-bounds
        }
        unsigned hv[8];
#pragma unroll
        for (int j = 0; j < 8; ++j) {
            const int src = (int)(((unsigned)pk[j].w) >> 16);
            hv[j] = h32[(src << 5) + s];
        }
#pragma unroll
        for (int j = 0; j < 8; ++j) {
            const f16x2 a01 = u2h((unsigned)pk[j].x);
            const f16x2 a23 = u2h((unsigned)pk[j].y);
            const f16x2 a45 = u2h((unsigned)pk[j].z);
            const f16x2 a6x = u2h((unsigned)pk[j].w);
            f16x2 ee = beh;
            ee += (f16x2){a01[0], a01[0]} * w0;
            ee += (f16x2){a01[1], a01[1]} * w1;
            ee += (f16x2){a23[0], a23[0]} * w2;
            ee += (f16x2){a23[1], a23[1]} * w3;
            ee += (f16x2){a45[0], a45[0]} * w4;
            ee += (f16x2){a45[1], a45[1]} * w5;
            ee += (f16x2){a6x[0], a6x[0]} * w6;
            f16x2 m2 = u2h(hv[j]) + ee;
            const _Float16 zz = (_Float16)0.f;
            m2 = (f16x2){ m2[0] > zz ? m2[0] : zz, m2[1] > zz ? m2[1] : zz };
            const float mf = vld[j] ? 1.f : 0.f;
            aLo = fmaf(mf, (float)m2[0], aLo);
            aHi = fmaf(mf, (float)m2[1], aHi);
        }
    }
    const f16x2 hn2 = u2h(h32[(n << 5) + s]);
    const float e1f = 1.0f + epsp[0];
    const float zLo = fmaf(e1f, (float)hn2[0], aLo);
    const float zHi = fmaf(e1f, (float)hn2[1], aHi);
    z32[(n << 5) + s] = h2u(__floats2half2_rn(zLo, zHi));
}

// ---------------------------------------------------------------------------
// MM1 (MFMA f16): y1 = z16 @ W1 + b1, f16 out. Block = 64 rows, 4 waves;
// B-frags direct from pre-swizzled W1s (L2-hot). In-register stats.
// ---------------------------------------------------------------------------
__global__ __launch_bounds__(256) void mm1_kernel(
    const _Float16* __restrict__ z16, const _Float16* __restrict__ W1s,
    const float* __restrict__ b1p, _Float16* __restrict__ y1h,
    float* __restrict__ part1)
{
    __shared__ float smS[4][128], smQ[4][128];
    const int t = threadIdx.x;
    const int wv = t >> 6, lane = t & 63;
    const int q = lane >> 4, ln = lane & 15;
    const int r0 = blockIdx.x << 6;

    const int rowm = r0 + (wv << 4) + ln;
    const f16x8 af0 = *(const f16x8*)(z16 + rowm * 64 + (q << 3));
    const f16x8 af1 = *(const f16x8*)(z16 + rowm * 64 + 32 + (q << 3));

    f32x4 acc[8];
#pragma unroll
    for (int n0 = 0; n0 < 8; ++n0) acc[n0] = (f32x4){0.f, 0.f, 0.f, 0.f};
#pragma unroll
    for (int n0 = 0; n0 < 8; ++n0) {
        const f16x8 bf0 = *(const f16x8*)(W1s + (((q << 7) + (n0 << 4) + ln) << 3));
        const f16x8 bf1 = *(const f16x8*)(W1s + ((((4 + q) << 7) + (n0 << 4) + ln) << 3));
        acc[n0] = __builtin_amdgcn_mfma_f32_16x16x32_f16(af0, bf0, acc[n0], 0, 0, 0);
        acc[n0] = __builtin_amdgcn_mfma_f32_16x16x32_f16(af1, bf1, acc[n0], 0, 0, 0);
    }

    const int baseRow = r0 + (wv << 4) + (q << 2);
#pragma unroll
    for (int n0 = 0; n0 < 8; ++n0) {
        const int col = (n0 << 4) + ln;
        const float bb = b1p[col];
        float s = 0.f, sq = 0.f;
#pragma unroll
        for (int rg = 0; rg < 4; ++rg) {
            const int row = baseRow + rg;
            const float y = acc[n0][rg] + bb;
            y1h[row * 128 + col] = (_Float16)y;
            const float m = (row < NN) ? 1.f : 0.f;
            s = fmaf(m, y, s); sq = fmaf(m, y * y, sq);
        }
        s += __shfl_xor(s, 16); s += __shfl_xor(s, 32);
        sq += __shfl_xor(sq, 16); sq += __shfl_xor(sq, 32);
        if (lane < 16) { smS[wv][col] = s; smQ[wv][col] = sq; }
    }
    __syncthreads();
    if (t < 128) {
        const float s = smS[0][t] + smS[1][t] + smS[2][t] + smS[3][t];
        const float q2 = smQ[0][t] + smQ[1][t] + smQ[2][t] + smQ[3][t];
        part1[(blockIdx.x << 8) + t] = s;
        part1[(blockIdx.x << 8) + 128 + t] = q2;
    }
}

// ---------------------------------------------------------------------------
// MM2 (MFMA f16): y2 = relu(bn1(y1h)) @ W2 + b2 (f32 out). Block = 64 rows.
// y2 row-aliases y1h (A reads complete before epilogue stores).
// ---------------------------------------------------------------------------
__global__ __launch_bounds__(256) void mm2_kernel(
    const _Float16* __restrict__ y1h, const float* __restrict__ scsh1,
    const _Float16* __restrict__ W2s, const float* __restrict__ b2,
    float* __restrict__ y2, float* __restrict__ part2)
{
    __shared__ float smS[4][64], smQ[4][64];
    const int t = threadIdx.x;
    const int wv = t >> 6, lane = t & 63;
    const int q = lane >> 4, ln = lane & 15;
    const int r0 = blockIdx.x << 6;

    const int rowm = r0 + (wv << 4) + ln;
    f16x8 af[4];
#pragma unroll
    for (int ks = 0; ks < 4; ++ks) {
        const int k0 = (ks << 5) + (q << 3);
        const f16x8 raw = *(const f16x8*)(y1h + rowm * 128 + k0);
        const float4 scA = *(const float4*)(scsh1 + k0);
        const float4 scB = *(const float4*)(scsh1 + k0 + 4);
        const float4 shA = *(const float4*)(scsh1 + 128 + k0);
        const float4 shB = *(const float4*)(scsh1 + 128 + k0 + 4);
        const float sc[8] = {scA.x, scA.y, scA.z, scA.w, scB.x, scB.y, scB.z, scB.w};
        const float sh[8] = {shA.x, shA.y, shA.z, shA.w, shB.x, shB.y, shB.z, shB.w};
        f16x8 a;
#pragma unroll
        for (int j = 0; j < 8; ++j)
            a[j] = (_Float16)fmaxf(fmaf((float)raw[j], sc[j], sh[j]), 0.f);
        af[ks] = a;
    }

    f32x4 acc[4];
#pragma unroll
    for (int n0 = 0; n0 < 4; ++n0) acc[n0] = (f32x4){0.f, 0.f, 0.f, 0.f};
#pragma unroll
    for (int n0 = 0; n0 < 4; ++n0) {
#pragma unroll
        for (int ks = 0; ks < 4; ++ks) {
            const f16x8 bf = *(const f16x8*)(
                W2s + (((((ks << 2) + q) << 6) + (n0 << 4) + ln) << 3));
            acc[n0] = __builtin_amdgcn_mfma_f32_16x16x32_f16(af[ks], bf, acc[n0], 0, 0, 0);
        }
    }

    const int baseRow = r0 + (wv << 4) + (q << 2);
#pragma unroll
    for (int n0 = 0; n0 < 4; ++n0) {
        const int col = (n0 << 4) + ln;
        const float bb = b2[col];
        float s = 0.f, sq = 0.f;
#pragma unroll
        for (int rg = 0; rg < 4; ++rg) {
            const int row = baseRow + rg;
            const float y = acc[n0][rg] + bb;
            y2[row * 64 + col] = y;
            const float m = (row < NN) ? 1.f : 0.f;
            s = fmaf(m, y, s); sq = fmaf(m, y * y, sq);
        }
        s += __shfl_xor(s, 16); s += __shfl_xor(s, 32);
        sq += __shfl_xor(sq, 16); sq += __shfl_xor(sq, 32);
        if (lane < 16) { smS[wv][col] = s; smQ[wv][col] = sq; }
    }
    __syncthreads();
    if (t < 64) {
        const float s = smS[0][t] + smS[1][t] + smS[2][t] + smS[3][t];
        const float q2 = smQ[0][t] + smQ[1][t] + smQ[2][t] + smQ[3][t];
        part2[(blockIdx.x << 7) + t] = s;
        part2[(blockIdx.x << 7) + 64 + t] = q2;
    }
}

// ---------------------------------------------------------------------------
// Final: out = bn2(y2) of layer 4 (no relu on last layer).
// ---------------------------------------------------------------------------
__global__ __launch_bounds__(256) void final_kernel(
    const float* __restrict__ y2, const float* __restrict__ scsh2,
    float* __restrict__ out)
{
    const int i = (blockIdx.x << 8) + threadIdx.x;
    if (i >= NN * 64) return;
    const int d = i & 63;
    out[i] = fmaf(y2[i], scsh2[d], scsh2[64 + d]);
}

extern "C" void kernel_launch(void* const* d_in, const int* in_sizes, int n_in,
                              void* d_out, int out_size, void* d_ws, size_t ws_size,
                              hipStream_t stream)
{
    const int*   x    = (const int*)d_in[0];
    const int*   ei   = (const int*)d_in[1];
    const float* ea   = (const float*)d_in[2];
    const float* nemb = (const float*)d_in[3];
    const float* We   = (const float*)d_in[4];
    const float* be   = (const float*)d_in[5];
    const float* eps  = (const float*)d_in[6];
    const float* W1   = (const float*)d_in[7];
    const float* b1   = (const float*)d_in[8];
    const float* g1   = (const float*)d_in[9];
    const float* bb1  = (const float*)d_in[10];
    const float* W2   = (const float*)d_in[11];
    const float* b2   = (const float*)d_in[12];
    const float* g2   = (const float*)d_in[13];
    const float* bb2  = (const float*)d_in[14];
    float* out = (float*)d_out;

    // workspace layout (4-byte word offsets); total 10,097,920 words = 40.4 MB
    int*      iws   = (int*)d_ws;
    float*    fws   = (float*)d_ws;
    int*      off   = iws + 0;          // 50001
    int*      deg   = iws + 50048;      // 50000
    int*      cur   = iws + 100096;     // 50000
    int*      bsum  = iws + 150144;     // 256
    float*    scsh1 = fws + 150400;     // 256 (sc128, sh128)
    float*    scsh2 = fws + 150656;     // 128 (sc64, sh64)
    float*    part1 = fws + 150784;     // 782*256 (row-major [bid][256])
    float*    part2 = fws + 350976;     // 782*128 (row-major [bid][128])
    _Float16* W1s   = (_Float16*)(fws + 451072);  // 5*8192 f16 swizzled
    _Float16* W2s   = (_Float16*)(fws + 471552);  // 5*8192 f16 swizzled
    unsigned* Wepk  = (unsigned*)(fws + 492032);  // 5*7*32 half2 (1120 words)
    unsigned* be2   = (unsigned*)(fws + 493152);  // 5*32 half2 (160 words)
    int4*     pea   = (int4*)(iws + 493312);      // 800000 x 16B
    _Float16* z16   = (_Float16*)(fws + 3693312); // 50048 x 64 f16 (padded)
    _Float16* y1h   = (_Float16*)(fws + 5294848); // 50048 x 128 f16 } row-
    float*    y2    = fws + 5294848;              // 50048 x 64 f32  } aliased
    __half*   h16   = (__half*)(fws + 8497920);   // 50000 x 64 f16

    hipMemsetAsync(deg, 0, 50000 * sizeof(int), stream);

    hist_kernel   <<<3125, 256, 0, stream>>>(ei, deg);
    scanA_kernel  <<<196,  256, 0, stream>>>(deg, bsum);
    scanB_kernel  <<<1,    256, 0, stream>>>(bsum);
    scanC_kernel  <<<196,  256, 0, stream>>>(deg, bsum, off, cur);
    scatter_kernel<<<3125, 256, 0, stream>>>(ei, ea, cur, pea);
    wprep_kernel  <<<325,  256, 0, stream>>>(W1, W2, We, be, W1s, W2s, Wepk, be2);
    hprep0_kernel <<<3125, 256, 0, stream>>>(x, nemb, h16);

    for (int l = 0; l < 5; ++l) {
        gather_kernel<<<6250, 256, 0, stream>>>(
            off, pea, (const unsigned*)h16, Wepk + l * 224, be2 + l * 32,
            eps + l, (unsigned*)z16);

        mm1_kernel<<<NB, 256, 0, stream>>>(z16, W1s + l * 8192, b1 + l * 128,
                                           y1h, part1);

        bnstats_kernel<<<128, 256, 0, stream>>>(part1, NB, 128,
                                                g1 + l * 128, bb1 + l * 128, scsh1);

        mm2_kernel<<<NB, 256, 0, stream>>>(y1h, scsh1, W2s + l * 8192, b2 + l * 64,
                                           y2, part2);

        bnstats_kernel<<<64, 256, 0, stream>>>(part2, NB, 64,
                                               g2 + l * 64, bb2 + l * 64, scsh2);

        if (l < 4)
            hprep_kernel<<<3125, 256, 0, stream>>>(y2, scsh2, h16);
    }

    final_kernel<<<12500, 256, 0, stream>>>(y2, scsh2, out);
}